// Round 3
// baseline (469.109 us; speedup 1.0000x reference)
//
#include <hip/hip_runtime.h>
#include <hip/hip_bf16.h>
#include <stdint.h>

typedef __bf16 bf16;
typedef __bf16 bf16x8 __attribute__((ext_vector_type(8)));
typedef __bf16 bf16x4 __attribute__((ext_vector_type(4)));
typedef float  f32x4  __attribute__((ext_vector_type(4)));

#define AS_GLOBAL __attribute__((address_space(1)))
#define AS_LDS    __attribute__((address_space(3)))

__device__ __forceinline__ void gload_lds16(const bf16* g, bf16* l) {
    __builtin_amdgcn_global_load_lds((const AS_GLOBAL uint32_t*)g,
                                     (AS_LDS uint32_t*)l, 16, 0, 0);
}
__device__ __forceinline__ void cfence() { asm volatile("" ::: "memory"); }
#define BARRIER() do { cfence(); __builtin_amdgcn_s_barrier(); cfence(); } while (0)
#define WAITV(n)  asm volatile("s_waitcnt vmcnt(" #n ")" ::: "memory")

// ---------------- convert fp32 -> bf16, 4 elems/thread ----------------
__global__ __launch_bounds__(256) void cvt_f32_to_bf16(const float* __restrict__ in,
                                                       bf16* __restrict__ out, int n4) {
    int i = blockIdx.x * 256 + threadIdx.x;
    if (i >= n4) return;
    const float4* p = (const float4*)in;
    float4 v = p[i];
    bf16x4 o;
    o[0] = (bf16)v.x; o[1] = (bf16)v.y; o[2] = (bf16)v.z; o[3] = (bf16)v.w;
    *(bf16x4*)(out + (size_t)i * 4) = o;
}

// ============ 4-phase/K-tile GEMM with one-phase-ahead fragment prefetch ============
// C[M,N] = A[M,K] * B[N,K]^T. BM=256, BK=64, 512 thr = 8 waves (2M x 4N).
// Phases: p0: a0xbl, p1: a0xbh, p2: a1xbh, p3: a1xbl. Reads issued one phase
// before use (bh@p0, a1@p1, a0(t+1)+bl(t+1)@p3-post-drain) -> LDS pipe overlaps
// MFMA. Only bl is reg-double-buffered (liveness). One fenced barrier per phase.
// Stages: B1(t+1)@p0 pre-bar, B0(t+2)@p2 post-bar, A0/A1(t+2)@p3 post-bar;
// counted vmcnt(2) at p3 drains exactly tile t+1 (8 oldest loads).
template<typename CT, int BN>
__global__ __launch_bounds__(512, 2) void gemm8p(const bf16* __restrict__ A,
                                                 const bf16* __restrict__ B,
                                                 CT* __restrict__ C,
                                                 int M, int N, int K, float scale) {
    constexpr int NBH  = BN / 128;        // B halves per K-tile (1 or 2)
    constexpr int BBUF = NBH * 16384;     // B bytes per K-tile buffer
    constexpr int WN   = BN / 4;          // wave N span (64 or 32)
    constexpr int NR   = WN / 16;         // n-reps (4 or 2)
    constexpr int NH   = NR / 2;          // n-reps per half (2 or 1)
    __shared__ char smem[65536 + 2 * BBUF];

    const int tid  = threadIdx.x;
    const int lane = tid & 63;
    const int wr   = (tid >> 6) >> 2;     // 0..1
    const int wc   = (tid >> 6) & 3;      // 0..3
    const int frow = lane & 15;
    const int fg   = lane >> 4;           // 0..3
    const int xorv = (frow & 7) << 4;

    const int nbn = N / BN;
    const int cpx = gridDim.x >> 3;
    const int swz = ((int)blockIdx.x & 7) * cpx + ((int)blockIdx.x >> 3);
    const int bm = swz / nbn, bn = swz % nbn;
    const int NT = K >> 6;                // even for all our shapes

    // staging map (inverse-swizzled source, linear LDS dest)
    const int prow0 = tid >> 3,         c0 = ((tid & 7) ^ (prow0 & 7)) << 3;
    const int prow1 = (tid + 512) >> 3, c1 = ((tid & 7) ^ (prow1 & 7)) << 3;
    const bf16* Asrc0 = A + (size_t)(bm * 256 + prow0) * K + c0;
    const bf16* Asrc1 = A + (size_t)(bm * 256 + prow1) * K + c1;
    const bf16* Bsrc0 = B + (size_t)(bn * BN  + prow0) * K + c0;
    const bf16* Bsrc1 = B + (size_t)(bn * BN  + prow1) * K + c1;

    auto stA = [&](int t, int h) {
        char* d = smem + ((t & 1) << 15) + (h << 14) + (tid << 4);
        gload_lds16(Asrc0 + (size_t)(h * 128) * K + t * 64, (bf16*)d);
        gload_lds16(Asrc1 + (size_t)(h * 128) * K + t * 64, (bf16*)(d + 8192));
    };
    auto stB = [&](int t, int h) {
        char* d = smem + 65536 + (t & 1) * BBUF + (h << 14) + (tid << 4);
        gload_lds16(Bsrc0 + (size_t)(h * 128) * K + t * 64, (bf16*)d);
        gload_lds16(Bsrc1 + (size_t)(h * 128) * K + t * 64, (bf16*)(d + 8192));
    };
    auto rdA = [&](int t, int m, int kk) -> bf16x8 {
        return *(const bf16x8*)(smem + ((t & 1) << 15) + (wr << 14)
                + (m * 16 + frow) * 128 + ((kk * 64 + (fg << 4)) ^ xorv));
    };
    auto rdB = [&](int t, int n, int kk) -> bf16x8 {
        int br = wc * WN + n * 16 + frow;
        return *(const bf16x8*)(smem + 65536 + (t & 1) * BBUF + ((br >> 7) << 14)
                + (br & 127) * 128 + ((kk * 64 + (fg << 4)) ^ xorv));
    };

    f32x4 acc[8][NR] = {};
    bf16x8 a0[4][2], a1[4][2], bhf[NH][2], blA[NH][2], blB[NH][2];

#define MM4(ACC, AF, BF) \
    _Pragma("unroll") for (int m_ = 0; m_ < 4; ++m_) \
    _Pragma("unroll") for (int n_ = 0; n_ < NH; ++n_) \
    _Pragma("unroll") for (int k_ = 0; k_ < 2; ++k_) \
        ACC = __builtin_amdgcn_mfma_f32_16x16x32_bf16(AF, BF, ACC, 0, 0, 0);

#define TILE(T, BLC, BLN) { \
    const int t1_ = (T) + 1, t2_ = (T) + 2; \
    /* ---- p0: read bh(T); stage B1(t+1); MFMA a0 x bl -> acc[0..3][lo] */ \
    if (NBH == 2 && t1_ < NT) stB(t1_, 1); \
    _Pragma("unroll") for (int n_ = 0; n_ < NH; ++n_) \
        { bhf[n_][0] = rdB((T), NH + n_, 0); bhf[n_][1] = rdB((T), NH + n_, 1); } \
    BARRIER(); \
    __builtin_amdgcn_s_setprio(1); \
    MM4(acc[m_][n_], a0[m_][k_], BLC[n_][k_]); \
    __builtin_amdgcn_s_setprio(0); \
    /* ---- p1: read a1(T); MFMA a0 x bh -> acc[0..3][hi] */ \
    _Pragma("unroll") for (int m_ = 0; m_ < 4; ++m_) \
        { a1[m_][0] = rdA((T), m_ + 4, 0); a1[m_][1] = rdA((T), m_ + 4, 1); } \
    BARRIER(); \
    __builtin_amdgcn_s_setprio(1); \
    MM4(acc[m_][NH + n_], a0[m_][k_], bhf[n_][k_]); \
    __builtin_amdgcn_s_setprio(0); \
    /* ---- p2: stage B0(t+2) post-bar; MFMA a1 x bh -> acc[4..7][hi] */ \
    BARRIER(); \
    if (t2_ < NT) stB(t2_, 0); \
    __builtin_amdgcn_s_setprio(1); \
    MM4(acc[m_ + 4][NH + n_], a1[m_][k_], bhf[n_][k_]); \
    __builtin_amdgcn_s_setprio(0); \
    /* ---- p3: drain t+1; stage A(t+2); read a0(t+1), bl(t+1); MFMA a1 x bl */ \
    if (t2_ < NT)      { WAITV(2); } \
    else if (t1_ < NT) { WAITV(0); } \
    BARRIER(); \
    if (t2_ < NT) { stA(t2_, 0); stA(t2_, 1); } \
    if (t1_ < NT) { \
        _Pragma("unroll") for (int m_ = 0; m_ < 4; ++m_) \
            { a0[m_][0] = rdA(t1_, m_, 0); a0[m_][1] = rdA(t1_, m_, 1); } \
        _Pragma("unroll") for (int n_ = 0; n_ < NH; ++n_) \
            { BLN[n_][0] = rdB(t1_, n_, 0); BLN[n_][1] = rdB(t1_, n_, 1); } \
    } \
    __builtin_amdgcn_s_setprio(1); \
    MM4(acc[m_ + 4][n_], a1[m_][k_], BLC[n_][k_]); \
    __builtin_amdgcn_s_setprio(0); \
}

    // prologue: tile0 (8 or 6 loads) + B0(1) + A0(1)+A1(1) (6 loads)
    stB(0, 0); if (NBH == 2) stB(0, 1);
    stA(0, 0); stA(0, 1);
    stB(1, 0);
    stA(1, 0); stA(1, 1);
    WAITV(6);
    BARRIER();
    #pragma unroll
    for (int m_ = 0; m_ < 4; ++m_) { a0[m_][0] = rdA(0, m_, 0); a0[m_][1] = rdA(0, m_, 1); }
    #pragma unroll
    for (int n_ = 0; n_ < NH; ++n_) { blA[n_][0] = rdB(0, n_, 0); blA[n_][1] = rdB(0, n_, 1); }

    for (int t = 0; t < NT; t += 2) {
        TILE(t,     blA, blB);
        TILE(t + 1, blB, blA);
    }
#undef TILE
#undef MM4

    // epilogue: C/D layout col = lane&15, row = (lane>>4)*4 + i
    const size_t crow0 = (size_t)bm * 256 + wr * 128 + (fg << 2);
    const size_t ccol0 = (size_t)bn * BN + wc * WN + frow;
    #pragma unroll
    for (int m = 0; m < 8; ++m)
        #pragma unroll
        for (int n = 0; n < NR; ++n)
            #pragma unroll
            for (int i = 0; i < 4; ++i)
                C[(crow0 + m * 16 + i) * N + ccol0 + n * 16] = (CT)(acc[m][n][i] * scale);
}

// ---------------- row softmax in place over bf16 [rows x 8192], reg-resident ----------------
__global__ __launch_bounds__(256) void softmax_row(bf16* __restrict__ Z, int cols) {
    __shared__ float red[4];
    const int tid = threadIdx.x;
    bf16* zrow = Z + (size_t)blockIdx.x * cols;

    float f[32];
    float lmax = -3.4e38f;
    #pragma unroll
    for (int it = 0; it < 4; ++it) {
        bf16x8 v = *(const bf16x8*)(zrow + it * 2048 + tid * 8);
        #pragma unroll
        for (int j = 0; j < 8; ++j) {
            f[it * 8 + j] = (float)v[j];
            lmax = fmaxf(lmax, f[it * 8 + j]);
        }
    }
    #pragma unroll
    for (int o = 32; o; o >>= 1) lmax = fmaxf(lmax, __shfl_xor(lmax, o));
    if ((tid & 63) == 0) red[tid >> 6] = lmax;
    __syncthreads();
    const float gmax = fmaxf(fmaxf(red[0], red[1]), fmaxf(red[2], red[3]));
    __syncthreads();

    float lsum = 0.f;
    #pragma unroll
    for (int i = 0; i < 32; ++i) {
        f[i] = __expf(f[i] - gmax);
        lsum += f[i];
    }
    #pragma unroll
    for (int o = 32; o; o >>= 1) lsum += __shfl_xor(lsum, o);
    if ((tid & 63) == 0) red[tid >> 6] = lsum;
    __syncthreads();
    const float inv = 1.0f / (red[0] + red[1] + red[2] + red[3]);

    #pragma unroll
    for (int it = 0; it < 4; ++it) {
        bf16x8 v;
        #pragma unroll
        for (int j = 0; j < 8; ++j) v[j] = (bf16)(f[it * 8 + j] * inv);
        *(bf16x8*)(zrow + it * 2048 + tid * 8) = v;
    }
}

// ---------------- bf16 transpose: VT[c][r] = V[r][c] ----------------
__global__ __launch_bounds__(256) void transpose_bf16(const ushort* __restrict__ V,
                                                      ushort* __restrict__ VT,
                                                      int R, int Ccols) {
    __shared__ ushort tile[32][33];
    const int tx = threadIdx.x, ty = threadIdx.y;
    const int r0 = blockIdx.y * 32, c0 = blockIdx.x * 32;
    #pragma unroll
    for (int i = 0; i < 32; i += 8)
        tile[ty + i][tx] = V[(size_t)(r0 + ty + i) * Ccols + c0 + tx];
    __syncthreads();
    #pragma unroll
    for (int i = 0; i < 32; i += 8)
        VT[(size_t)(c0 + ty + i) * R + r0 + tx] = tile[tx][ty + i];
}

extern "C" void kernel_launch(void* const* d_in, const int* in_sizes, int n_in,
                              void* d_out, int out_size, void* d_ws, size_t ws_size,
                              hipStream_t stream) {
    const float* h  = (const float*)d_in[0];
    const float* wq = (const float*)d_in[1];
    const float* wk = (const float*)d_in[2];
    const float* wv = (const float*)d_in[3];
    float* out = (float*)d_out;

    char* ws = (char*)d_ws;
    bf16* h_bf  = (bf16*)(ws);                          // 16 MB  [8192 x 1024]
    bf16* wq_bf = (bf16*)(ws + (16ull << 20));          //  2 MB
    bf16* wk_bf = (bf16*)(ws + (18ull << 20));          //  2 MB
    bf16* wv_bf = (bf16*)(ws + (20ull << 20));          //  2 MB
    bf16* Q     = (bf16*)(ws + (22ull << 20));          // 16 MB
    bf16* Kb    = (bf16*)(ws + (38ull << 20));          // 16 MB
    bf16* V     = (bf16*)(ws + (54ull << 20));          // 16 MB
    bf16* VT    = (bf16*)(ws + (70ull << 20));          // 16 MB  [1024 x 8192]
    bf16* Z     = (bf16*)(ws + (86ull << 20));          // 128 MB [8192 x 8192]

    // 1) convert inputs to bf16
    cvt_f32_to_bf16<<<8192, 256, 0, stream>>>(h,  h_bf,  (8192 * 1024) / 4);
    cvt_f32_to_bf16<<<1024, 256, 0, stream>>>(wq, wq_bf, (1024 * 1024) / 4);
    cvt_f32_to_bf16<<<1024, 256, 0, stream>>>(wk, wk_bf, (1024 * 1024) / 4);
    cvt_f32_to_bf16<<<1024, 256, 0, stream>>>(wv, wv_bf, (1024 * 1024) / 4);

    // 2) Q = h @ wq^T (scale folded), K = h @ wk^T, V = h @ wv^T   (BN=128)
    const float qscale = 1.0f / 32.0f;   // 1/sqrt(1024)
    gemm8p<bf16, 128><<<256, 512, 0, stream>>>(h_bf, wq_bf, Q,  8192, 1024, 1024, qscale);
    gemm8p<bf16, 128><<<256, 512, 0, stream>>>(h_bf, wk_bf, Kb, 8192, 1024, 1024, 1.0f);
    gemm8p<bf16, 128><<<256, 512, 0, stream>>>(h_bf, wv_bf, V,  8192, 1024, 1024, 1.0f);

    // 3) VT = V^T
    transpose_bf16<<<dim3(1024 / 32, 8192 / 32), dim3(32, 8), 0, stream>>>(
        (const ushort*)V, (ushort*)VT, 8192, 1024);

    // 4) Z = Q @ K^T  (scaled logits, bf16; BN=256 -> 1024 blocks)
    gemm8p<bf16, 256><<<1024, 512, 0, stream>>>(Q, Kb, Z, 8192, 8192, 1024, 1.0f);

    // 5) row softmax in place
    softmax_row<<<8192, 256, 0, stream>>>(Z, 8192);

    // 6) out = beta @ V  ==  beta[8192,8192] @ VT[1024,8192]^T   (BN=128)
    gemm8p<float, 128><<<256, 512, 0, stream>>>(Z, VT, out, 8192, 1024, 8192, 1.0f);
}

// Round 4
// 432.287 us; speedup vs baseline: 1.0852x; 1.0852x over previous
//
#include <hip/hip_runtime.h>
#include <hip/hip_bf16.h>
#include <stdint.h>

typedef __bf16 bf16;
typedef __bf16 bf16x8 __attribute__((ext_vector_type(8)));
typedef __bf16 bf16x4 __attribute__((ext_vector_type(4)));
typedef float  f32x4  __attribute__((ext_vector_type(4)));

#define AS_GLOBAL __attribute__((address_space(1)))
#define AS_LDS    __attribute__((address_space(3)))

__device__ __forceinline__ void gload_lds16(const bf16* g, bf16* l) {
    __builtin_amdgcn_global_load_lds((const AS_GLOBAL uint32_t*)g,
                                     (AS_LDS uint32_t*)l, 16, 0, 0);
}
__device__ __forceinline__ void cfence() { asm volatile("" ::: "memory"); }
#define BAR()    do { cfence(); __builtin_amdgcn_s_barrier(); cfence(); } while (0)
#define WAITV(n) asm volatile("s_waitcnt vmcnt(" #n ")" ::: "memory")

// ---------------- convert fp32 -> bf16, 4 elems/thread ----------------
__global__ __launch_bounds__(256) void cvt_f32_to_bf16(const float* __restrict__ in,
                                                       bf16* __restrict__ out, int n4) {
    int i = blockIdx.x * 256 + threadIdx.x;
    if (i >= n4) return;
    const float4* p = (const float4*)in;
    float4 v = p[i];
    bf16x4 o;
    o[0] = (bf16)v.x; o[1] = (bf16)v.y; o[2] = (bf16)v.z; o[3] = (bf16)v.w;
    *(bf16x4*)(out + (size_t)i * 4) = o;
}

// ======= 4-phase prefetched GEMM: C[M,N] = A[M,K] * B[N,K]^T, tile 256x128 =======
// 512 thr = 8 waves (4M x 2N), wave tile 64x64 -> acc 64 VGPR, frags 80 VGPR (no spill).
// Phase = [counted vmcnt][barrier][stage 1 half][ds_reads for NEXT phase][8 MFMA].
// Phase order p0:aLxbL p1:aLxbH p2:aHxbH p3:aHxbL. Reads: bH@p0, aH@p1,
// aL(t+1)+bL(t+1)@p3. Stages: B0(t+1)@p0, A0(t+2)@p1, B1(t+2)@p2, A1(t+2)@p3.
// Issue order per tile X: A0(X)[2], B1(X)[1], A1(X)[2], B0(X)[1] -> counted waits
// vmcnt(8)@p0 (forces B1(t)), vmcnt(7)@p1 (A1(t)), vmcnt(3)@p3 (B0(t+1)).
// vmcnt precedes the barrier -> staged-data visibility is collective.
// LDS halves remapped so each half == one fragment class:
//   A-half h rows (global) = { wr*64 + h*32 + [0,32) : wr in 0..3 }
//   B-half h rows (global) = { wc*64 + h*32 + [0,32) : wc in 0..1 }
// XOR swizzle (16B-slot ^= row&7) via inverse-swizzled global source (r2: 0 conflicts).
template<typename CT>
__global__ __launch_bounds__(512, 2) void gemm4q(const bf16* __restrict__ A,
                                                 const bf16* __restrict__ B,
                                                 CT* __restrict__ C,
                                                 int M, int N, int K, float scale) {
    __shared__ char smem[65536 + 32768];   // A: 2x32KB, B at +65536: 2x16KB

    const int tid  = threadIdx.x;
    const int lane = tid & 63;
    const int wave = tid >> 6;
    const int wr   = wave >> 1;           // 0..3
    const int wc   = wave & 1;            // 0..1
    const int frow = lane & 15;
    const int fg   = lane >> 4;           // 0..3

    const int nbn = N >> 7;
    const int cpx = gridDim.x >> 3;
    const int swz = ((int)blockIdx.x & 7) * cpx + ((int)blockIdx.x >> 3);
    const int bm = swz / nbn, bn = swz % nbn;
    const int NT = K >> 6;                // 16 or 128 (even, >= 4)

    // staging map: physical chunk s: prow = s>>3, pslot = s&7, logical slot = pslot^(prow&7)
    const int r0  = (((tid >> 8) & 1) << 6) + ((tid >> 3) & 31);  // global row base (chunk0)
    const int csw = (((tid & 7) ^ ((tid >> 3) & 7)) << 3);        // inv-swizzled col
    const bf16* Abase = A + (size_t)(bm * 128 * 2 + r0) * K + csw;
    const bf16* Bbase = B + (size_t)(bn * 128 + r0) * K + csw;

    auto stA = [&](int t, int h) {        // 2 loads
        char* d = smem + ((t & 1) << 15) + (h << 14) + (tid << 4);
        gload_lds16(Abase + (size_t)(h * 32) * K + t * 64, (bf16*)d);
        gload_lds16(Abase + (size_t)(h * 32 + 128) * K + t * 64, (bf16*)(d + 8192));
    };
    auto stB = [&](int t, int h) {        // 1 load
        char* d = smem + 65536 + ((t & 1) << 14) + (h << 13) + (tid << 4);
        gload_lds16(Bbase + (size_t)(h * 32) * K + t * 64, (bf16*)d);
    };
    auto rdA = [&](int t, int i, int kk) -> bf16x8 {   // i in [0,4)
        int row = wr * 32 + ((i & 1) << 4) + frow;
        return *(const bf16x8*)(smem + ((t & 1) << 15) + ((i >> 1) << 14)
                + row * 128 + ((((kk << 2) + fg) ^ (frow & 7)) << 4));
    };
    auto rdB = [&](int t, int j, int kk) -> bf16x8 {   // j in [0,4)
        int row = wc * 32 + ((j & 1) << 4) + frow;
        return *(const bf16x8*)(smem + 65536 + ((t & 1) << 14) + ((j >> 1) << 13)
                + row * 128 + ((((kk << 2) + fg) ^ (frow & 7)) << 4));
    };

    f32x4 acc[4][4] = {};
    bf16x8 aL[2][2], aH[2][2], bH[2][2], bLa[2][2], bLb[2][2];

#define MM8(IO, AR, JO, BR) \
    _Pragma("unroll") for (int i_ = 0; i_ < 2; ++i_) \
    _Pragma("unroll") for (int j_ = 0; j_ < 2; ++j_) \
    _Pragma("unroll") for (int k_ = 0; k_ < 2; ++k_) \
        acc[i_ + IO][j_ + JO] = __builtin_amdgcn_mfma_f32_16x16x32_bf16( \
            AR[i_][k_], BR[j_][k_], acc[i_ + IO][j_ + JO], 0, 0, 0);

#define TILE(T, BLC, BLN) { \
    const int t1_ = (T) + 1, t2_ = (T) + 2; \
    /* p0: aL x bL */ \
    if (t1_ < NT) { WAITV(8); } else { WAITV(3); } \
    BAR(); \
    if (t1_ < NT) stB(t1_, 0); \
    _Pragma("unroll") for (int j_ = 0; j_ < 2; ++j_) \
    _Pragma("unroll") for (int k_ = 0; k_ < 2; ++k_) bH[j_][k_] = rdB((T), j_ + 2, k_); \
    __builtin_amdgcn_s_setprio(1); MM8(0, aL, 0, BLC); __builtin_amdgcn_s_setprio(0); \
    /* p1: aL x bH */ \
    if (t1_ < NT) { WAITV(7); } else { WAITV(1); } \
    BAR(); \
    if (t2_ < NT) stA(t2_, 0); \
    _Pragma("unroll") for (int i_ = 0; i_ < 2; ++i_) \
    _Pragma("unroll") for (int k_ = 0; k_ < 2; ++k_) aH[i_][k_] = rdA((T), i_ + 2, k_); \
    __builtin_amdgcn_s_setprio(1); MM8(0, aL, 2, bH); __builtin_amdgcn_s_setprio(0); \
    /* p2: aH x bH */ \
    BAR(); \
    if (t2_ < NT) stB(t2_, 1); \
    __builtin_amdgcn_s_setprio(1); MM8(2, aH, 2, bH); __builtin_amdgcn_s_setprio(0); \
    /* p3: aH x bL ; prefetch tile t+1 fragments */ \
    if (t2_ < NT) { WAITV(3); } else { WAITV(0); } \
    BAR(); \
    if (t2_ < NT) stA(t2_, 1); \
    if (t1_ < NT) { \
        _Pragma("unroll") for (int i_ = 0; i_ < 2; ++i_) \
        _Pragma("unroll") for (int k_ = 0; k_ < 2; ++k_) aL[i_][k_] = rdA(t1_, i_, k_); \
        _Pragma("unroll") for (int j_ = 0; j_ < 2; ++j_) \
        _Pragma("unroll") for (int k_ = 0; k_ < 2; ++k_) BLN[j_][k_] = rdB(t1_, j_, k_); \
    } \
    __builtin_amdgcn_s_setprio(1); MM8(2, aH, 0, BLC); __builtin_amdgcn_s_setprio(0); \
}

    // prologue: issue order A0(0),B1(0),A1(0),B0(0),A0(1),B1(1),A1(1)  (11 loads)
    stA(0, 0);
    stB(0, 1);
    stA(0, 1);
    stB(0, 0);
    stA(1, 0);
    stB(1, 1);
    stA(1, 1);
    WAITV(5);           // force A0(0),B1(0),A1(0),B0(0) landed; 5 newer in flight
    BAR();
    #pragma unroll
    for (int i_ = 0; i_ < 2; ++i_)
        #pragma unroll
        for (int k_ = 0; k_ < 2; ++k_) aL[i_][k_] = rdA(0, i_, k_);
    #pragma unroll
    for (int j_ = 0; j_ < 2; ++j_)
        #pragma unroll
        for (int k_ = 0; k_ < 2; ++k_) bLa[j_][k_] = rdB(0, j_, k_);

    for (int t = 0; t < NT; t += 2) {
        TILE(t,     bLa, bLb);
        TILE(t + 1, bLb, bLa);
    }
#undef TILE
#undef MM8

    // epilogue: C/D layout col = lane&15, row = (lane>>4)*4 + ii
    const size_t crow0 = (size_t)bm * 256 + wr * 64 + (fg << 2);
    const size_t ccol0 = (size_t)bn * 128 + wc * 64 + frow;
    #pragma unroll
    for (int i = 0; i < 4; ++i)
        #pragma unroll
        for (int j = 0; j < 4; ++j)
            #pragma unroll
            for (int ii = 0; ii < 4; ++ii)
                C[(crow0 + i * 16 + ii) * N + ccol0 + j * 16] = (CT)(acc[i][j][ii] * scale);
}

// ---------------- row softmax in place over bf16 [rows x 8192], reg-resident ----------------
__global__ __launch_bounds__(256) void softmax_row(bf16* __restrict__ Z, int cols) {
    __shared__ float red[4];
    const int tid = threadIdx.x;
    bf16* zrow = Z + (size_t)blockIdx.x * cols;

    float f[32];
    float lmax = -3.4e38f;
    #pragma unroll
    for (int it = 0; it < 4; ++it) {
        bf16x8 v = *(const bf16x8*)(zrow + it * 2048 + tid * 8);
        #pragma unroll
        for (int j = 0; j < 8; ++j) {
            f[it * 8 + j] = (float)v[j];
            lmax = fmaxf(lmax, f[it * 8 + j]);
        }
    }
    #pragma unroll
    for (int o = 32; o; o >>= 1) lmax = fmaxf(lmax, __shfl_xor(lmax, o));
    if ((tid & 63) == 0) red[tid >> 6] = lmax;
    __syncthreads();
    const float gmax = fmaxf(fmaxf(red[0], red[1]), fmaxf(red[2], red[3]));
    __syncthreads();

    float lsum = 0.f;
    #pragma unroll
    for (int i = 0; i < 32; ++i) {
        f[i] = __expf(f[i] - gmax);
        lsum += f[i];
    }
    #pragma unroll
    for (int o = 32; o; o >>= 1) lsum += __shfl_xor(lsum, o);
    if ((tid & 63) == 0) red[tid >> 6] = lsum;
    __syncthreads();
    const float inv = 1.0f / (red[0] + red[1] + red[2] + red[3]);

    #pragma unroll
    for (int it = 0; it < 4; ++it) {
        bf16x8 v;
        #pragma unroll
        for (int j = 0; j < 8; ++j) v[j] = (bf16)(f[it * 8 + j] * inv);
        *(bf16x8*)(zrow + it * 2048 + tid * 8) = v;
    }
}

// ---------------- bf16 transpose: VT[c][r] = V[r][c] ----------------
__global__ __launch_bounds__(256) void transpose_bf16(const ushort* __restrict__ V,
                                                      ushort* __restrict__ VT,
                                                      int R, int Ccols) {
    __shared__ ushort tile[32][33];
    const int tx = threadIdx.x, ty = threadIdx.y;
    const int r0 = blockIdx.y * 32, c0 = blockIdx.x * 32;
    #pragma unroll
    for (int i = 0; i < 32; i += 8)
        tile[ty + i][tx] = V[(size_t)(r0 + ty + i) * Ccols + c0 + tx];
    __syncthreads();
    #pragma unroll
    for (int i = 0; i < 32; i += 8)
        VT[(size_t)(c0 + ty + i) * R + r0 + tx] = tile[tx][ty + i];
}

extern "C" void kernel_launch(void* const* d_in, const int* in_sizes, int n_in,
                              void* d_out, int out_size, void* d_ws, size_t ws_size,
                              hipStream_t stream) {
    const float* h  = (const float*)d_in[0];
    const float* wq = (const float*)d_in[1];
    const float* wk = (const float*)d_in[2];
    const float* wv = (const float*)d_in[3];
    float* out = (float*)d_out;

    char* ws = (char*)d_ws;
    bf16* h_bf  = (bf16*)(ws);                          // 16 MB  [8192 x 1024]
    bf16* wq_bf = (bf16*)(ws + (16ull << 20));          //  2 MB
    bf16* wk_bf = (bf16*)(ws + (18ull << 20));          //  2 MB
    bf16* wv_bf = (bf16*)(ws + (20ull << 20));          //  2 MB
    bf16* Q     = (bf16*)(ws + (22ull << 20));          // 16 MB
    bf16* Kb    = (bf16*)(ws + (38ull << 20));          // 16 MB
    bf16* V     = (bf16*)(ws + (54ull << 20));          // 16 MB
    bf16* VT    = (bf16*)(ws + (70ull << 20));          // 16 MB  [1024 x 8192]
    bf16* Z     = (bf16*)(ws + (86ull << 20));          // 128 MB [8192 x 8192]

    // 1) convert inputs to bf16
    cvt_f32_to_bf16<<<8192, 256, 0, stream>>>(h,  h_bf,  (8192 * 1024) / 4);
    cvt_f32_to_bf16<<<1024, 256, 0, stream>>>(wq, wq_bf, (1024 * 1024) / 4);
    cvt_f32_to_bf16<<<1024, 256, 0, stream>>>(wk, wk_bf, (1024 * 1024) / 4);
    cvt_f32_to_bf16<<<1024, 256, 0, stream>>>(wv, wv_bf, (1024 * 1024) / 4);

    // 2) Q = h @ wq^T (scale folded), K = h @ wk^T, V = h @ wv^T   (grid 32x8=256)
    const float qscale = 1.0f / 32.0f;   // 1/sqrt(1024)
    gemm4q<bf16><<<256, 512, 0, stream>>>(h_bf, wq_bf, Q,  8192, 1024, 1024, qscale);
    gemm4q<bf16><<<256, 512, 0, stream>>>(h_bf, wk_bf, Kb, 8192, 1024, 1024, 1.0f);
    gemm4q<bf16><<<256, 512, 0, stream>>>(h_bf, wv_bf, V,  8192, 1024, 1024, 1.0f);

    // 3) VT = V^T
    transpose_bf16<<<dim3(1024 / 32, 8192 / 32), dim3(32, 8), 0, stream>>>(
        (const ushort*)V, (ushort*)VT, 8192, 1024);

    // 4) Z = Q @ K^T  (scaled logits, bf16; grid 32x64 = 2048)
    gemm4q<bf16><<<2048, 512, 0, stream>>>(Q, Kb, Z, 8192, 8192, 1024, 1.0f);

    // 5) row softmax in place
    softmax_row<<<8192, 256, 0, stream>>>(Z, 8192);

    // 6) out = beta @ V  ==  beta[8192,8192] @ VT[1024,8192]^T   (grid 256, K=8192)
    gemm4q<float><<<256, 512, 0, stream>>>(Z, VT, out, 8192, 1024, 8192, 1.0f);
}

// Round 5
// 419.739 us; speedup vs baseline: 1.1176x; 1.0299x over previous
//
#include <hip/hip_runtime.h>
#include <hip/hip_bf16.h>
#include <stdint.h>

typedef __bf16 bf16;
typedef __bf16 bf16x8 __attribute__((ext_vector_type(8)));
typedef __bf16 bf16x4 __attribute__((ext_vector_type(4)));
typedef float  f32x4  __attribute__((ext_vector_type(4)));

#define AS_GLOBAL __attribute__((address_space(1)))
#define AS_LDS    __attribute__((address_space(3)))

__device__ __forceinline__ void gload_lds16(const bf16* g, bf16* l) {
    __builtin_amdgcn_global_load_lds((const AS_GLOBAL uint32_t*)g,
                                     (AS_LDS uint32_t*)l, 16, 0, 0);
}
__device__ __forceinline__ void cfence() { asm volatile("" ::: "memory"); }
#define BAR()    do { cfence(); __builtin_amdgcn_s_barrier(); cfence(); } while (0)
#define WAITV(n) asm volatile("s_waitcnt vmcnt(" #n ")" ::: "memory")

// ---------------- convert fp32 -> bf16, 4 elems/thread ----------------
__global__ __launch_bounds__(256) void cvt_f32_to_bf16(const float* __restrict__ in,
                                                       bf16* __restrict__ out, int n4) {
    int i = blockIdx.x * 256 + threadIdx.x;
    if (i >= n4) return;
    const float4* p = (const float4*)in;
    float4 v = p[i];
    bf16x4 o;
    o[0] = (bf16)v.x; o[1] = (bf16)v.y; o[2] = (bf16)v.z; o[3] = (bf16)v.w;
    *(bf16x4*)(out + (size_t)i * 4) = o;
}

// ========== m201-style 8-phase GEMM: C[M,N] = A[M,K] * B[N,K]^T ==========
// BM=256, BK=64, 512 thr = 8 waves (2M x 4N), wave tile 128 x BN/4.
// Per phase: [stage <=1 half][ds_reads for THIS phase][bar][setprio+MFMA][bar].
// Quadrants p0:(mlo,nlo) p1:(mlo,nhi) p2:(mhi,nhi) p3:(mhi,nlo).
// Reads: p0: aLo(8)+bLo(4|2); p1: bHi(4|2); p2: aHi(8); p3: none.
// Stages (race-derived): p0: B-last(t+1) [other buf, safe];
//   p2: B0(t+2) [B-reads done after p1-bar]; p3: A0(t+2)+A1(t+2) [A-reads done
//   after p2-bar]. vmcnt once per K-tile at p3 end: leaves exactly the t+2
//   halves (6 loads BN=256, 4 loads BN=128) in flight -> tile t+1 fully
//   landed + barrier => collectively visible.
// LDS halves: A0=rows0-127(wr=0), A1=rows128-255(wr=1); B likewise by wc>>1.
// XOR swizzle 16B-slot ^= (row&7): inverse-swizzled global source + swizzled
// ds_read (r2-measured: 0 bank conflicts).
template<typename CT, int BN>
__global__ __launch_bounds__(512, 2) void gemmQ(const bf16* __restrict__ A,
                                                const bf16* __restrict__ B,
                                                CT* __restrict__ C,
                                                int K, int lda, int ldb, int ldc,
                                                int nbn) {
    constexpr int NBH = BN / 128;         // B halves (2 or 1)
    constexpr int NR  = BN / 64;          // n-frags per wave (4 or 2)
    constexpr int NHF = NR / 2;           // n-frags per half-quadrant (2 or 1)
    __shared__ char smem[65536 + NBH * 32768];   // A 2x32KB | B 2x(NBH*16KB)

    const int tid  = threadIdx.x;
    const int lane = tid & 63;
    const int wave = tid >> 6;
    const int wr   = wave >> 2;           // 0..1
    const int wc   = wave & 3;            // 0..3
    const int frow = lane & 15;
    const int fg   = lane >> 4;           // 0..3

    const int cpx = gridDim.x >> 3;
    const int swz = ((int)blockIdx.x & 7) * cpx + ((int)blockIdx.x >> 3);
    const int bm = swz / nbn, bn = swz % nbn;
    const int NT = K >> 6;                // >= 2

    // staging map: chunk p: prow=p>>3, pslot=p&7 holds logical slot pslot^(prow&7)
    const int r0 = tid >> 3;                        // 0..63
    const int c0 = ((tid & 7) ^ (r0 & 7)) << 3;     // inv-swizzled col (elems)
    const bf16* Abase = A + (size_t)(bm * 256 + r0) * lda + c0;
    const bf16* Bbase = B + (size_t)(bn * BN + r0) * ldb + c0;

    auto stA = [&](int t, int h) {        // one 128x64 half = 2 loads/thread
        char* d = smem + ((t & 1) << 15) + (h << 14) + (tid << 4);
        gload_lds16(Abase + ((size_t)(h * 128)      ) * lda + t * 64, (bf16*)d);
        gload_lds16(Abase + ((size_t)(h * 128) + 64 ) * lda + t * 64, (bf16*)(d + 8192));
    };
    auto stB = [&](int t, int h) {
        char* d = smem + 65536 + (t & 1) * (NBH * 16384) + (h << 14) + (tid << 4);
        gload_lds16(Bbase + ((size_t)(h * 128)      ) * ldb + t * 64, (bf16*)d);
        gload_lds16(Bbase + ((size_t)(h * 128) + 64 ) * ldb + t * 64, (bf16*)(d + 8192));
    };
    auto rdA = [&](int t, int m, int kk) -> bf16x8 {   // m in [0,8)
        int r = m * 16 + frow;
        return *(const bf16x8*)(smem + ((t & 1) << 15) + (wr << 14)
                + r * 128 + ((((kk << 2) + fg) ^ (frow & 7)) << 4));
    };
    auto rdB = [&](int t, int n, int kk) -> bf16x8 {   // n in [0,NR)
        int br = wc * (BN / 4) + n * 16 + frow;
        return *(const bf16x8*)(smem + 65536 + (t & 1) * (NBH * 16384) + ((br >> 7) << 14)
                + (br & 127) * 128 + ((((kk << 2) + fg) ^ (frow & 7)) << 4));
    };

    f32x4 acc[8][NR] = {};
    bf16x8 aLo[4][2], aHi[4][2], bLo[NHF][2], bHi[NHF][2];

#define MMQ(MO, AARR, NO, BARR) \
    _Pragma("unroll") for (int m_ = 0; m_ < 4; ++m_) \
    _Pragma("unroll") for (int n_ = 0; n_ < NHF; ++n_) \
    _Pragma("unroll") for (int k_ = 0; k_ < 2; ++k_) \
        acc[m_ + MO][n_ + NO] = __builtin_amdgcn_mfma_f32_16x16x32_bf16( \
            AARR[m_][k_], BARR[n_][k_], acc[m_ + MO][n_ + NO], 0, 0, 0);

    // prologue: tile0 full + A0,A1(1) (+B0(1) if NBH==2); B-last(1) comes at t0/p0
    stA(0, 0); stA(0, 1);
    stB(0, 0); if constexpr (NBH == 2) stB(0, 1);
    stA(1, 0); stA(1, 1);
    if constexpr (NBH == 2) { stB(1, 0); WAITV(6); } else { WAITV(4); }
    BAR();

    for (int t = 0; t < NT; ++t) {
        // ---- p0: stage B-last(t+1); read aLo,bLo; MFMA (mlo,nlo)
        if (t + 1 < NT) stB(t + 1, NBH - 1);
        #pragma unroll
        for (int m_ = 0; m_ < 4; ++m_)
            #pragma unroll
            for (int k_ = 0; k_ < 2; ++k_) aLo[m_][k_] = rdA(t, m_, k_);
        #pragma unroll
        for (int n_ = 0; n_ < NHF; ++n_)
            #pragma unroll
            for (int k_ = 0; k_ < 2; ++k_) bLo[n_][k_] = rdB(t, n_, k_);
        BAR();
        __builtin_amdgcn_s_setprio(1); MMQ(0, aLo, 0, bLo); __builtin_amdgcn_s_setprio(0);
        BAR();
        // ---- p1: read bHi; MFMA (mlo,nhi)
        #pragma unroll
        for (int n_ = 0; n_ < NHF; ++n_)
            #pragma unroll
            for (int k_ = 0; k_ < 2; ++k_) bHi[n_][k_] = rdB(t, NHF + n_, k_);
        BAR();
        __builtin_amdgcn_s_setprio(1); MMQ(0, aLo, NHF, bHi); __builtin_amdgcn_s_setprio(0);
        BAR();
        // ---- p2: stage B0(t+2) [NBH==2]; read aHi; MFMA (mhi,nhi)
        if (NBH == 2 && t + 2 < NT) stB(t + 2, 0);
        #pragma unroll
        for (int m_ = 0; m_ < 4; ++m_)
            #pragma unroll
            for (int k_ = 0; k_ < 2; ++k_) aHi[m_][k_] = rdA(t, 4 + m_, k_);
        BAR();
        __builtin_amdgcn_s_setprio(1); MMQ(4, aHi, NHF, bHi); __builtin_amdgcn_s_setprio(0);
        BAR();
        // ---- p3: stage A0,A1(t+2); MFMA (mhi,nlo); counted drain; barrier
        if (t + 2 < NT) { stA(t + 2, 0); stA(t + 2, 1); }
        BAR();
        __builtin_amdgcn_s_setprio(1); MMQ(4, aHi, 0, bLo); __builtin_amdgcn_s_setprio(0);
        if (t + 2 < NT) {
            if constexpr (NBH == 2) WAITV(6); else WAITV(4);
        } else if (t + 1 < NT) {
            WAITV(0);
        }
        BAR();
    }
#undef MMQ

    // epilogue: C/D layout col = lane&15, row = (lane>>4)*4 + i
    const size_t crow0 = (size_t)bm * 256 + wr * 128 + (fg << 2);
    const size_t ccol0 = (size_t)bn * BN + wc * (BN / 4) + frow;
    #pragma unroll
    for (int m = 0; m < 8; ++m)
        #pragma unroll
        for (int n = 0; n < NR; ++n)
            #pragma unroll
            for (int i = 0; i < 4; ++i)
                C[(crow0 + m * 16 + i) * ldc + ccol0 + n * 16] = (CT)(acc[m][n][i]);
}

// ------- row softmax in place over bf16 [rows x 8192], applies logit scale -------
__global__ __launch_bounds__(256) void softmax_row(bf16* __restrict__ Z, int cols) {
    __shared__ float red[4];
    const int tid = threadIdx.x;
    bf16* zrow = Z + (size_t)blockIdx.x * cols;
    const float scale = 0.03125f;   // 1/sqrt(1024)

    float f[32];
    float lmax = -3.4e38f;
    #pragma unroll
    for (int it = 0; it < 4; ++it) {
        bf16x8 v = *(const bf16x8*)(zrow + it * 2048 + tid * 8);
        #pragma unroll
        for (int j = 0; j < 8; ++j) {
            f[it * 8 + j] = (float)v[j] * scale;
            lmax = fmaxf(lmax, f[it * 8 + j]);
        }
    }
    #pragma unroll
    for (int o = 32; o; o >>= 1) lmax = fmaxf(lmax, __shfl_xor(lmax, o));
    if ((tid & 63) == 0) red[tid >> 6] = lmax;
    __syncthreads();
    const float gmax = fmaxf(fmaxf(red[0], red[1]), fmaxf(red[2], red[3]));
    __syncthreads();

    float lsum = 0.f;
    #pragma unroll
    for (int i = 0; i < 32; ++i) {
        f[i] = __expf(f[i] - gmax);
        lsum += f[i];
    }
    #pragma unroll
    for (int o = 32; o; o >>= 1) lsum += __shfl_xor(lsum, o);
    if ((tid & 63) == 0) red[tid >> 6] = lsum;
    __syncthreads();
    const float inv = 1.0f / (red[0] + red[1] + red[2] + red[3]);

    #pragma unroll
    for (int it = 0; it < 4; ++it) {
        bf16x8 v;
        #pragma unroll
        for (int j = 0; j < 8; ++j) v[j] = (bf16)(f[it * 8 + j] * inv);
        *(bf16x8*)(zrow + it * 2048 + tid * 8) = v;
    }
}

// ------- bf16 transpose with input row stride: VT[c][r] = V[r*ld + c] -------
__global__ __launch_bounds__(256) void transpose_bf16(const ushort* __restrict__ V,
                                                      ushort* __restrict__ VT,
                                                      int R, int ld) {
    __shared__ ushort tile[32][33];
    const int tx = threadIdx.x, ty = threadIdx.y;
    const int r0 = blockIdx.y * 32, c0 = blockIdx.x * 32;
    #pragma unroll
    for (int i = 0; i < 32; i += 8)
        tile[ty + i][tx] = V[(size_t)(r0 + ty + i) * ld + c0 + tx];
    __syncthreads();
    #pragma unroll
    for (int i = 0; i < 32; i += 8)
        VT[(size_t)(c0 + ty + i) * R + r0 + tx] = tile[tx][ty + i];
}

extern "C" void kernel_launch(void* const* d_in, const int* in_sizes, int n_in,
                              void* d_out, int out_size, void* d_ws, size_t ws_size,
                              hipStream_t stream) {
    const float* h  = (const float*)d_in[0];
    const float* wq = (const float*)d_in[1];
    const float* wk = (const float*)d_in[2];
    const float* wv = (const float*)d_in[3];
    float* out = (float*)d_out;

    char* ws = (char*)d_ws;
    bf16* h_bf = (bf16*)(ws);                           // 16 MB [8192 x 1024]
    bf16* wcat = (bf16*)(ws + (16ull << 20));           //  6 MB [3072 x 1024] (wq|wk|wv)
    bf16* QKV  = (bf16*)(ws + (22ull << 20));           // 48 MB [8192 x 3072]
    bf16* VT   = (bf16*)(ws + (70ull << 20));           // 16 MB [1024 x 8192]
    bf16* Z    = (bf16*)(ws + (86ull << 20));           // 128 MB [8192 x 8192]

    // 1) convert inputs to bf16 (weights into one concatenated [3072,1024])
    cvt_f32_to_bf16<<<8192, 256, 0, stream>>>(h,  h_bf, (8192 * 1024) / 4);
    cvt_f32_to_bf16<<<1024, 256, 0, stream>>>(wq, wcat,                (1024 * 1024) / 4);
    cvt_f32_to_bf16<<<1024, 256, 0, stream>>>(wk, wcat + 1024 * 1024,  (1024 * 1024) / 4);
    cvt_f32_to_bf16<<<1024, 256, 0, stream>>>(wv, wcat + 2048 * 1024,  (1024 * 1024) / 4);

    // 2) QKV = h @ wcat^T : [8192 x 3072], grid 32x12 = 384
    gemmQ<bf16, 256><<<384, 512, 0, stream>>>(h_bf, wcat, QKV,
                                              1024, 1024, 1024, 3072, 12);

    // 3) VT = V^T (V = QKV[:, 2048:3072], row stride 3072)
    transpose_bf16<<<dim3(32, 256), dim3(32, 8), 0, stream>>>(
        (const ushort*)(QKV + 2048), (ushort*)VT, 8192, 3072);

    // 4) Z = Q @ K^T (unscaled logits; Q=QKV[:,0:1024], K=QKV[:,1024:2048])
    gemmQ<bf16, 256><<<1024, 512, 0, stream>>>(QKV, QKV + 1024, Z,
                                               1024, 3072, 3072, 8192, 32);

    // 5) row softmax in place (applies 1/32 logit scale)
    softmax_row<<<8192, 256, 0, stream>>>(Z, 8192);

    // 6) out = beta @ V == beta[8192,8192] @ VT[1024,8192]^T, grid 32x8 = 256
    gemmQ<float, 128><<<256, 512, 0, stream>>>(Z, VT, out,
                                               8192, 8192, 8192, 1024, 8);
}

// Round 6
// 409.056 us; speedup vs baseline: 1.1468x; 1.0261x over previous
//
#include <hip/hip_runtime.h>
#include <hip/hip_bf16.h>
#include <stdint.h>

typedef __bf16 bf16;
typedef __bf16 bf16x8 __attribute__((ext_vector_type(8)));
typedef __bf16 bf16x4 __attribute__((ext_vector_type(4)));
typedef float  f32x4  __attribute__((ext_vector_type(4)));

#define AS_GLOBAL __attribute__((address_space(1)))
#define AS_LDS    __attribute__((address_space(3)))

__device__ __forceinline__ void gload_lds16(const bf16* g, bf16* l) {
    __builtin_amdgcn_global_load_lds((const AS_GLOBAL uint32_t*)g,
                                     (AS_LDS uint32_t*)l, 16, 0, 0);
}
__device__ __forceinline__ void cfence() { asm volatile("" ::: "memory"); }
#define BAR()    do { cfence(); __builtin_amdgcn_s_barrier(); cfence(); } while (0)
#define WAITV(n) asm volatile("s_waitcnt vmcnt(" #n ")" ::: "memory")
#define WAITL0() asm volatile("s_waitcnt lgkmcnt(0)" ::: "memory")

// ---------------- convert fp32 -> bf16, 4 elems/thread ----------------
__global__ __launch_bounds__(256) void cvt_f32_to_bf16(const float* __restrict__ in,
                                                       bf16* __restrict__ out, int n4) {
    int i = blockIdx.x * 256 + threadIdx.x;
    if (i >= n4) return;
    const float4* p = (const float4*)in;
    float4 v = p[i];
    bf16x4 o;
    o[0] = (bf16)v.x; o[1] = (bf16)v.y; o[2] = (bf16)v.z; o[3] = (bf16)v.w;
    *(bf16x4*)(out + (size_t)i * 4) = o;
}

// ====== phase-shifted 8-phase GEMM: C[M,N] = A[M,K] * B[N,K]^T (+split-K) ======
// BM=256, BK=64, 512 thr = 8 waves (2M x 4N), wave tile 128 x BN/4.
// Reads have >=1 phase of slack before their consuming MFMA:
//   reads:  p0: aLo(8)   p1: bHi(4) [+bLo(4) after MFMA]   p2: aHi(8)   p3: 0
//   MFMA:   p0: Q2(t-1)=(mhi,nhi)  p1: Q3(t-1)=(mhi,nlo)
//           p2: Q0(t)  =(mlo,nlo)  p3: Q1(t)  =(mlo,nhi)   (epilogue: Q2,Q3(NT-1))
// All fragment arrays single-buffered (next-tile read strictly after last use).
// Stages: Blast(t+1)@p0, B0(t+2)@p2 (NBH==2), A0+A1(t+2)@p3.
// Stage-vs-pending-read races closed by lgkmcnt(0) before p1/p2 end barriers.
// vmcnt once per K-tile at p3: 6 (NBH=2) / 4 (NBH=1) => tile t+1 fully landed.
// XOR swizzle 16B-slot ^= (row&7) via inverse-swizzled global source (0 conflicts, r2).
template<typename CT, int BN, int SPLIT>
__global__ __launch_bounds__(512, 2) void gemmQ(const bf16* __restrict__ A,
                                                const bf16* __restrict__ B,
                                                CT* __restrict__ C,
                                                CT* __restrict__ C2,
                                                int K, int lda, int ldb, int ldc,
                                                int nbn) {
    constexpr int NBH = BN / 128;         // B halves (2 or 1)
    constexpr int NR  = BN / 64;          // n-frags per wave (4 or 2)
    constexpr int NHF = NR / 2;           // n-frags per half-quadrant (2 or 1)
    __shared__ char smem[65536 + NBH * 32768];

    const int tid  = threadIdx.x;
    const int lane = tid & 63;
    const int wave = tid >> 6;
    const int wr   = wave >> 2;           // 0..1
    const int wc   = wave & 3;            // 0..3
    const int frow = lane & 15;
    const int fg   = lane >> 4;           // 0..3

    const int cpx = gridDim.x >> 3;
    const int swz = ((int)blockIdx.x & 7) * cpx + ((int)blockIdx.x >> 3);
    int id = swz, s = 0;
    if (SPLIT == 2) { s = id & 1; id >>= 1; }
    const int bm = id / nbn, bn = id % nbn;
    const int NT = K >> 6;                // even, >= 4
    const size_t koff = (size_t)s * K;
    CT* Cp = (SPLIT == 2 && s == 1) ? C2 : C;

    // staging map: chunk p: prow=p>>3, pslot=p&7 holds logical slot pslot^(prow&7)
    const int r0 = tid >> 3;                        // 0..63
    const int c0 = ((tid & 7) ^ (r0 & 7)) << 3;     // inv-swizzled col (elems)
    const bf16* Abase = A + (size_t)(bm * 256 + r0) * lda + c0 + koff;
    const bf16* Bbase = B + (size_t)(bn * BN + r0) * ldb + c0 + koff;

    auto stA = [&](int t, int h) {        // one 128x64 half = 2 loads/thread
        char* d = smem + ((t & 1) << 15) + (h << 14) + (tid << 4);
        gload_lds16(Abase + ((size_t)(h * 128)      ) * lda + t * 64, (bf16*)d);
        gload_lds16(Abase + ((size_t)(h * 128) + 64 ) * lda + t * 64, (bf16*)(d + 8192));
    };
    auto stB = [&](int t, int h) {
        char* d = smem + 65536 + (t & 1) * (NBH * 16384) + (h << 14) + (tid << 4);
        gload_lds16(Bbase + ((size_t)(h * 128)      ) * ldb + t * 64, (bf16*)d);
        gload_lds16(Bbase + ((size_t)(h * 128) + 64 ) * ldb + t * 64, (bf16*)(d + 8192));
    };
    auto rdA = [&](int t, int m, int kk) -> bf16x8 {   // m in [0,8)
        int r = m * 16 + frow;
        return *(const bf16x8*)(smem + ((t & 1) << 15) + (wr << 14)
                + r * 128 + ((((kk << 2) + fg) ^ (frow & 7)) << 4));
    };
    auto rdB = [&](int t, int n, int kk) -> bf16x8 {   // n in [0,NR)
        int br = wc * (BN / 4) + n * 16 + frow;
        return *(const bf16x8*)(smem + 65536 + (t & 1) * (NBH * 16384) + ((br >> 7) << 14)
                + (br & 127) * 128 + ((((kk << 2) + fg) ^ (frow & 7)) << 4));
    };

    f32x4 acc[8][NR] = {};
    bf16x8 aLo[4][2], aHi[4][2], bLo[NHF][2], bHi[NHF][2];

#define MMQ(MO, NO, AARR, BARR) \
    _Pragma("unroll") for (int m_ = 0; m_ < 4; ++m_) \
    _Pragma("unroll") for (int n_ = 0; n_ < NHF; ++n_) \
    _Pragma("unroll") for (int k_ = 0; k_ < 2; ++k_) \
        acc[m_ + MO][n_ + NO] = __builtin_amdgcn_mfma_f32_16x16x32_bf16( \
            AARR[m_][k_], BARR[n_][k_], acc[m_ + MO][n_ + NO], 0, 0, 0);

    // prologue: tile0 full + A(1) (+B0(1) if NBH==2); Blast(1) staged at p0(0)
    stA(0, 0); stA(0, 1);
    stB(0, 0); if constexpr (NBH == 2) stB(0, 1);
    stA(1, 0); stA(1, 1);
    if constexpr (NBH == 2) { stB(1, 0); WAITV(6); } else { WAITV(4); }
    BAR();

    for (int t = 0; t < NT; ++t) {
        // ---- p0: stage Blast(t+1); read aLo(t); MFMA Q2(t-1)
        if (t + 1 < NT) stB(t + 1, NBH - 1);
        #pragma unroll
        for (int m_ = 0; m_ < 4; ++m_)
            #pragma unroll
            for (int k_ = 0; k_ < 2; ++k_) aLo[m_][k_] = rdA(t, m_, k_);
        BAR();
        if (t > 0) {
            __builtin_amdgcn_s_setprio(1); MMQ(4, NHF, aHi, bHi); __builtin_amdgcn_s_setprio(0);
        }
        BAR();
        // ---- p1: read bHi(t); MFMA Q3(t-1); read bLo(t) after (WAR by prog order)
        #pragma unroll
        for (int n_ = 0; n_ < NHF; ++n_)
            #pragma unroll
            for (int k_ = 0; k_ < 2; ++k_) bHi[n_][k_] = rdB(t, NHF + n_, k_);
        BAR();
        if (t > 0) {
            __builtin_amdgcn_s_setprio(1); MMQ(4, 0, aHi, bLo); __builtin_amdgcn_s_setprio(0);
        }
        #pragma unroll
        for (int n_ = 0; n_ < NHF; ++n_)
            #pragma unroll
            for (int k_ = 0; k_ < 2; ++k_) bLo[n_][k_] = rdB(t, n_, k_);
        WAITL0();   // bLo/bHi landed before anyone stages B0(t+2)
        BAR();
        // ---- p2: stage B0(t+2); read aHi(t); MFMA Q0(t)
        if (NBH == 2 && t + 2 < NT) stB(t + 2, 0);
        #pragma unroll
        for (int m_ = 0; m_ < 4; ++m_)
            #pragma unroll
            for (int k_ = 0; k_ < 2; ++k_) aHi[m_][k_] = rdA(t, 4 + m_, k_);
        BAR();
        __builtin_amdgcn_s_setprio(1); MMQ(0, 0, aLo, bLo); __builtin_amdgcn_s_setprio(0);
        WAITL0();   // all A reads landed before anyone stages A(t+2)
        BAR();
        // ---- p3: stage A0,A1(t+2); MFMA Q1(t); counted drain
        if (t + 2 < NT) { stA(t + 2, 0); stA(t + 2, 1); }
        BAR();
        __builtin_amdgcn_s_setprio(1); MMQ(0, NHF, aLo, bHi); __builtin_amdgcn_s_setprio(0);
        if (t + 2 < NT) {
            if constexpr (NBH == 2) WAITV(6); else WAITV(4);
        } else if (t + 1 < NT) {
            WAITV(0);
        }
        BAR();
    }
    // epilogue MFMAs: Q2(NT-1), Q3(NT-1)
    __builtin_amdgcn_s_setprio(1);
    MMQ(4, NHF, aHi, bHi);
    MMQ(4, 0, aHi, bLo);
    __builtin_amdgcn_s_setprio(0);
#undef MMQ

    // epilogue: C/D layout col = lane&15, row = (lane>>4)*4 + i
    const size_t crow0 = (size_t)bm * 256 + wr * 128 + (fg << 2);
    const size_t ccol0 = (size_t)bn * BN + wc * (BN / 4) + frow;
    #pragma unroll
    for (int m = 0; m < 8; ++m)
        #pragma unroll
        for (int n = 0; n < NR; ++n)
            #pragma unroll
            for (int i = 0; i < 4; ++i)
                Cp[(crow0 + m * 16 + i) * ldc + ccol0 + n * 16] = (CT)(acc[m][n][i]);
}

// ---------------- out[i] += part[i], float4 ----------------
__global__ __launch_bounds__(256) void add_f32(float* __restrict__ out,
                                               const float* __restrict__ part, int n4) {
    int i = blockIdx.x * 256 + threadIdx.x;
    if (i >= n4) return;
    float4 a = ((const float4*)out)[i];
    float4 b = ((const float4*)part)[i];
    a.x += b.x; a.y += b.y; a.z += b.z; a.w += b.w;
    ((float4*)out)[i] = a;
}

// ------- row softmax in place over bf16 [rows x 8192], applies logit scale -------
__global__ __launch_bounds__(256) void softmax_row(bf16* __restrict__ Z, int cols) {
    __shared__ float red[4];
    const int tid = threadIdx.x;
    bf16* zrow = Z + (size_t)blockIdx.x * cols;
    const float scale = 0.03125f;   // 1/sqrt(1024)

    float f[32];
    float lmax = -3.4e38f;
    #pragma unroll
    for (int it = 0; it < 4; ++it) {
        bf16x8 v = *(const bf16x8*)(zrow + it * 2048 + tid * 8);
        #pragma unroll
        for (int j = 0; j < 8; ++j) {
            f[it * 8 + j] = (float)v[j] * scale;
            lmax = fmaxf(lmax, f[it * 8 + j]);
        }
    }
    #pragma unroll
    for (int o = 32; o; o >>= 1) lmax = fmaxf(lmax, __shfl_xor(lmax, o));
    if ((tid & 63) == 0) red[tid >> 6] = lmax;
    __syncthreads();
    const float gmax = fmaxf(fmaxf(red[0], red[1]), fmaxf(red[2], red[3]));
    __syncthreads();

    float lsum = 0.f;
    #pragma unroll
    for (int i = 0; i < 32; ++i) {
        f[i] = __expf(f[i] - gmax);
        lsum += f[i];
    }
    #pragma unroll
    for (int o = 32; o; o >>= 1) lsum += __shfl_xor(lsum, o);
    if ((tid & 63) == 0) red[tid >> 6] = lsum;
    __syncthreads();
    const float inv = 1.0f / (red[0] + red[1] + red[2] + red[3]);

    #pragma unroll
    for (int it = 0; it < 4; ++it) {
        bf16x8 v;
        #pragma unroll
        for (int j = 0; j < 8; ++j) v[j] = (bf16)(f[it * 8 + j] * inv);
        *(bf16x8*)(zrow + it * 2048 + tid * 8) = v;
    }
}

// ------- bf16 transpose with input row stride: VT[c][r] = V[r*ld + c] -------
__global__ __launch_bounds__(256) void transpose_bf16(const ushort* __restrict__ V,
                                                      ushort* __restrict__ VT,
                                                      int R, int ld) {
    __shared__ ushort tile[32][33];
    const int tx = threadIdx.x, ty = threadIdx.y;
    const int r0 = blockIdx.y * 32, c0 = blockIdx.x * 32;
    #pragma unroll
    for (int i = 0; i < 32; i += 8)
        tile[ty + i][tx] = V[(size_t)(r0 + ty + i) * ld + c0 + tx];
    __syncthreads();
    #pragma unroll
    for (int i = 0; i < 32; i += 8)
        VT[(size_t)(c0 + ty + i) * R + r0 + tx] = tile[tx][ty + i];
}

extern "C" void kernel_launch(void* const* d_in, const int* in_sizes, int n_in,
                              void* d_out, int out_size, void* d_ws, size_t ws_size,
                              hipStream_t stream) {
    const float* h  = (const float*)d_in[0];
    const float* wq = (const float*)d_in[1];
    const float* wk = (const float*)d_in[2];
    const float* wv = (const float*)d_in[3];
    float* out = (float*)d_out;

    char* ws = (char*)d_ws;
    bf16*  h_bf = (bf16*)(ws);                          // 16 MB [8192 x 1024]
    bf16*  wcat = (bf16*)(ws + (16ull << 20));          //  6 MB [3072 x 1024]
    bf16*  QKV  = (bf16*)(ws + (22ull << 20));          // 48 MB [8192 x 3072]
    bf16*  VT   = (bf16*)(ws + (70ull << 20));          // 16 MB [1024 x 8192]
    bf16*  Z    = (bf16*)(ws + (86ull << 20));          // 128 MB [8192 x 8192]
    float* Pv   = (float*)(ws);                         // 32 MB partial (h_bf/wcat dead by PV)

    // 1) convert inputs to bf16 (weights concatenated [3072,1024])
    cvt_f32_to_bf16<<<8192, 256, 0, stream>>>(h,  h_bf, (8192 * 1024) / 4);
    cvt_f32_to_bf16<<<1024, 256, 0, stream>>>(wq, wcat,               (1024 * 1024) / 4);
    cvt_f32_to_bf16<<<1024, 256, 0, stream>>>(wk, wcat + 1024 * 1024, (1024 * 1024) / 4);
    cvt_f32_to_bf16<<<1024, 256, 0, stream>>>(wv, wcat + 2048 * 1024, (1024 * 1024) / 4);

    // 2) QKV = h @ wcat^T : [8192 x 3072], grid 384
    gemmQ<bf16, 256, 1><<<384, 512, 0, stream>>>(h_bf, wcat, QKV, nullptr,
                                                 1024, 1024, 1024, 3072, 12);

    // 3) VT = V^T (V = QKV[:, 2048:3072], row stride 3072)
    transpose_bf16<<<dim3(32, 256), dim3(32, 8), 0, stream>>>(
        (const ushort*)(QKV + 2048), (ushort*)VT, 8192, 3072);

    // 4) Z = Q @ K^T (unscaled logits), grid 1024
    gemmQ<bf16, 256, 1><<<1024, 512, 0, stream>>>(QKV, QKV + 1024, Z, nullptr,
                                                  1024, 3072, 3072, 8192, 32);

    // 5) row softmax in place (applies 1/32 logit scale)
    softmax_row<<<8192, 256, 0, stream>>>(Z, 8192);

    // 6) out = beta @ V: split-K=2 at BN=256, grid 32m x 4n x 2s = 256
    gemmQ<float, 256, 2><<<256, 512, 0, stream>>>(Z, VT, out, Pv,
                                                  4096, 8192, 8192, 1024, 4);
    add_f32<<<8192, 256, 0, stream>>>(out, Pv, (8192 * 1024) / 4);
}

// Round 7
// 377.336 us; speedup vs baseline: 1.2432x; 1.0841x over previous
//
#include <hip/hip_runtime.h>
#include <hip/hip_bf16.h>
#include <stdint.h>
#include <math.h>

typedef __bf16 bf16;
typedef __bf16 bf16x8 __attribute__((ext_vector_type(8)));
typedef __bf16 bf16x4 __attribute__((ext_vector_type(4)));
typedef float  f32x4  __attribute__((ext_vector_type(4)));

#define AS_GLOBAL __attribute__((address_space(1)))
#define AS_LDS    __attribute__((address_space(3)))

__device__ __forceinline__ void gload_lds16(const bf16* g, bf16* l) {
    __builtin_amdgcn_global_load_lds((const AS_GLOBAL uint32_t*)g,
                                     (AS_LDS uint32_t*)l, 16, 0, 0);
}
__device__ __forceinline__ void cfence() { asm volatile("" ::: "memory"); }
#define BAR()    do { cfence(); __builtin_amdgcn_s_barrier(); cfence(); } while (0)
#define WAITV(n) asm volatile("s_waitcnt vmcnt(" #n ")" ::: "memory")
#define WAITL0() asm volatile("s_waitcnt lgkmcnt(0)" ::: "memory")

// ---------------- convert fp32 -> bf16, 4 elems/thread ----------------
__global__ __launch_bounds__(256) void cvt_f32_to_bf16(const float* __restrict__ in,
                                                       bf16* __restrict__ out, int n4) {
    int i = blockIdx.x * 256 + threadIdx.x;
    if (i >= n4) return;
    const float4* p = (const float4*)in;
    float4 v = p[i];
    bf16x4 o;
    o[0] = (bf16)v.x; o[1] = (bf16)v.y; o[2] = (bf16)v.z; o[3] = (bf16)v.w;
    *(bf16x4*)(out + (size_t)i * 4) = o;
}

// ====== 2-window/K-tile GEMM: C[M,N] = A[M,K] * B[N,K]^T (+split-K, +epilogues) ======
// BM=256, BK=64, 512 thr = 8 waves (2M x 4N), wave tile 128 x BN/4.
// Only 2 barriers per K-tile (the minimum the LDS hazards require):
//  W1: stage Blast(t+1) [other-parity buf]; 24 ds_reads of tile t; 32 MFMA (Q0,Q1);
//      lgkmcnt(0)  [all 8 waves' reads of buf t&1 drained];  barrier.
//  W2: stage A0,A1,B0(t+2) [same-parity buf, safe after bar]; 32 reg-only MFMA (Q2,Q3);
//      vmcnt(6) [forces every tile-(t+1) load complete, leaves t+2's 6 in flight]; barrier.
// Compiler inserts counted lgkm waits inside W1 so reads overlap the Q0/Q1 MFMAs.
// XOR swizzle 16B-slot ^= (row&7) via inverse-swizzled global source (r2/r6: 0 conflicts).
// EPI: 0 = plain cast; 1 = bf16 exp(acc/32) (unnormalized softmax numerator).
template<typename CT, int BN, int SPLIT, int EPI>
__global__ __launch_bounds__(512, 2) void gemmW(const bf16* __restrict__ A,
                                                const bf16* __restrict__ B,
                                                CT* __restrict__ C,
                                                CT* __restrict__ C2,
                                                int K, int lda, int ldb, int ldc,
                                                int nbn) {
    constexpr int NBH = BN / 128;         // B halves (2 or 1)
    constexpr int NR  = BN / 64;          // n-frags per wave (4 or 2)
    constexpr int NHF = NR / 2;           // n-frags per half (2 or 1)
    __shared__ char smem[65536 + NBH * 32768];

    const int tid  = threadIdx.x;
    const int lane = tid & 63;
    const int wave = tid >> 6;
    const int wr   = wave >> 2;           // 0..1
    const int wc   = wave & 3;            // 0..3
    const int frow = lane & 15;
    const int fg   = lane >> 4;           // 0..3

    const int cpx = gridDim.x >> 3;
    const int swz = ((int)blockIdx.x & 7) * cpx + ((int)blockIdx.x >> 3);
    int id = swz, s = 0;
    if (SPLIT == 2) { s = id & 1; id >>= 1; }
    const int bm = id / nbn, bn = id % nbn;
    const int NT = K >> 6;                // >= 4
    const size_t koff = (size_t)s * K;
    CT* Cp = (SPLIT == 2 && s == 1) ? C2 : C;

    // staging map: chunk p: prow=p>>3, pslot=p&7 holds logical slot pslot^(prow&7)
    const int r0 = tid >> 3;                        // 0..63
    const int c0 = ((tid & 7) ^ (r0 & 7)) << 3;     // inv-swizzled col (elems)
    const bf16* Abase = A + (size_t)(bm * 256 + r0) * lda + c0 + koff;
    const bf16* Bbase = B + (size_t)(bn * BN + r0) * ldb + c0 + koff;

    auto stA = [&](int t, int h) {        // one 128x64 half = 2 loads/thread
        char* d = smem + ((t & 1) << 15) + (h << 14) + (tid << 4);
        gload_lds16(Abase + ((size_t)(h * 128)      ) * lda + t * 64, (bf16*)d);
        gload_lds16(Abase + ((size_t)(h * 128) + 64 ) * lda + t * 64, (bf16*)(d + 8192));
    };
    auto stB = [&](int t, int h) {
        char* d = smem + 65536 + (t & 1) * (NBH * 16384) + (h << 14) + (tid << 4);
        gload_lds16(Bbase + ((size_t)(h * 128)      ) * ldb + t * 64, (bf16*)d);
        gload_lds16(Bbase + ((size_t)(h * 128) + 64 ) * ldb + t * 64, (bf16*)(d + 8192));
    };
    auto rdA = [&](int t, int m, int kk) -> bf16x8 {   // m in [0,8)
        int r = m * 16 + frow;
        return *(const bf16x8*)(smem + ((t & 1) << 15) + (wr << 14)
                + r * 128 + ((((kk << 2) + fg) ^ (frow & 7)) << 4));
    };
    auto rdB = [&](int t, int n, int kk) -> bf16x8 {   // n in [0,NR)
        int br = wc * (BN / 4) + n * 16 + frow;
        return *(const bf16x8*)(smem + 65536 + (t & 1) * (NBH * 16384) + ((br >> 7) << 14)
                + (br & 127) * 128 + ((((kk << 2) + fg) ^ (frow & 7)) << 4));
    };

    f32x4 acc[8][NR] = {};
    bf16x8 aLo[4][2], aHi[4][2], bLo[NHF][2], bHi[NHF][2];

#define MMQ(MO, NO, AARR, BARR) \
    _Pragma("unroll") for (int m_ = 0; m_ < 4; ++m_) \
    _Pragma("unroll") for (int n_ = 0; n_ < NHF; ++n_) \
    _Pragma("unroll") for (int k_ = 0; k_ < 2; ++k_) \
        acc[m_ + MO][n_ + NO] = __builtin_amdgcn_mfma_f32_16x16x32_bf16( \
            AARR[m_][k_], BARR[n_][k_], acc[m_ + MO][n_ + NO], 0, 0, 0);

    // prologue: tile0 full + tile1 A0,A1 (+B0 if NBH==2); Blast(1) staged in W1(t=0)
    stA(0, 0); stA(0, 1);
    stB(0, 0); if constexpr (NBH == 2) stB(0, 1);
    stA(1, 0); stA(1, 1);
    if constexpr (NBH == 2) { stB(1, 0); WAITV(6); } else { WAITV(4); }
    BAR();

    for (int t = 0; t < NT; ++t) {
        // ---------- window 1 ----------
        if (t + 1 < NT) stB(t + 1, NBH - 1);
        #pragma unroll
        for (int m_ = 0; m_ < 4; ++m_) { aLo[m_][0] = rdA(t, m_, 0); aLo[m_][1] = rdA(t, m_, 1); }
        #pragma unroll
        for (int n_ = 0; n_ < NHF; ++n_) { bLo[n_][0] = rdB(t, n_, 0); bLo[n_][1] = rdB(t, n_, 1); }
        #pragma unroll
        for (int n_ = 0; n_ < NHF; ++n_) { bHi[n_][0] = rdB(t, NHF + n_, 0); bHi[n_][1] = rdB(t, NHF + n_, 1); }
        #pragma unroll
        for (int m_ = 0; m_ < 4; ++m_) { aHi[m_][0] = rdA(t, 4 + m_, 0); aHi[m_][1] = rdA(t, 4 + m_, 1); }
        __builtin_amdgcn_s_setprio(1);
        MMQ(0, 0, aLo, bLo);
        MMQ(0, NHF, aLo, bHi);
        __builtin_amdgcn_s_setprio(0);
        WAITL0();            // all this wave's reads of buf t&1 complete before barrier
        BAR();
        // ---------- window 2 ----------
        if (t + 2 < NT) {
            stA(t + 2, 0); stA(t + 2, 1);
            if constexpr (NBH == 2) stB(t + 2, 0);
        }
        __builtin_amdgcn_s_setprio(1);
        MMQ(4, NHF, aHi, bHi);
        MMQ(4, 0, aHi, bLo);
        __builtin_amdgcn_s_setprio(0);
        if (t + 2 < NT) {
            if constexpr (NBH == 2) WAITV(6); else WAITV(4);
        } else if (t + 1 < NT) {
            WAITV(0);
        }
        BAR();
    }
#undef MMQ

    // epilogue: C/D layout col = lane&15, row = (lane>>4)*4 + i
    const size_t crow0 = (size_t)bm * 256 + wr * 128 + (fg << 2);
    const size_t ccol0 = (size_t)bn * BN + wc * (BN / 4) + frow;
    #pragma unroll
    for (int m = 0; m < 8; ++m)
        #pragma unroll
        for (int n = 0; n < NR; ++n)
            #pragma unroll
            for (int i = 0; i < 4; ++i) {
                float v = acc[m][n][i];
                if constexpr (EPI == 1) v = __expf(v * 0.03125f);   // exp(z/sqrt(1024))
                Cp[(crow0 + m * 16 + i) * ldc + ccol0 + n * 16] = (CT)v;
            }
}

// ------- rowsum of E [rows x 8192] bf16 -> inv[row] = 1/sum -------
__global__ __launch_bounds__(256) void rowsum_inv(const bf16* __restrict__ E,
                                                  float* __restrict__ inv, int cols) {
    __shared__ float red[4];
    const int tid = threadIdx.x;
    const bf16* er = E + (size_t)blockIdx.x * cols;
    float s = 0.f;
    #pragma unroll
    for (int it = 0; it < 4; ++it) {
        bf16x8 v = *(const bf16x8*)(er + it * 2048 + tid * 8);
        #pragma unroll
        for (int j = 0; j < 8; ++j) s += (float)v[j];
    }
    #pragma unroll
    for (int o = 32; o; o >>= 1) s += __shfl_xor(s, o);
    if ((tid & 63) == 0) red[tid >> 6] = s;
    __syncthreads();
    if (tid == 0) inv[blockIdx.x] = 1.0f / (red[0] + red[1] + red[2] + red[3]);
}

// ------- out[i] = (out[i] + part[i]) * inv[row], float4 -------
__global__ __launch_bounds__(256) void add_scale(float* __restrict__ out,
                                                 const float* __restrict__ part,
                                                 const float* __restrict__ inv, int n4) {
    int i = blockIdx.x * 256 + threadIdx.x;
    if (i >= n4) return;
    const float sc = inv[i >> 8];          // 256 float4 per 1024-wide row
    float4 a = ((const float4*)out)[i];
    float4 b = ((const float4*)part)[i];
    a.x = (a.x + b.x) * sc; a.y = (a.y + b.y) * sc;
    a.z = (a.z + b.z) * sc; a.w = (a.w + b.w) * sc;
    ((float4*)out)[i] = a;
}

// ------- bf16 transpose with input row stride: VT[c][r] = V[r*ld + c] -------
__global__ __launch_bounds__(256) void transpose_bf16(const ushort* __restrict__ V,
                                                      ushort* __restrict__ VT,
                                                      int R, int ld) {
    __shared__ ushort tile[32][33];
    const int tx = threadIdx.x, ty = threadIdx.y;
    const int r0 = blockIdx.y * 32, c0 = blockIdx.x * 32;
    #pragma unroll
    for (int i = 0; i < 32; i += 8)
        tile[ty + i][tx] = V[(size_t)(r0 + ty + i) * ld + c0 + tx];
    __syncthreads();
    #pragma unroll
    for (int i = 0; i < 32; i += 8)
        VT[(size_t)(c0 + ty + i) * R + r0 + tx] = tile[tx][ty + i];
}

extern "C" void kernel_launch(void* const* d_in, const int* in_sizes, int n_in,
                              void* d_out, int out_size, void* d_ws, size_t ws_size,
                              hipStream_t stream) {
    const float* h  = (const float*)d_in[0];
    const float* wq = (const float*)d_in[1];
    const float* wk = (const float*)d_in[2];
    const float* wv = (const float*)d_in[3];
    float* out = (float*)d_out;

    char* ws = (char*)d_ws;
    bf16*  h_bf = (bf16*)(ws);                          // 16 MB [8192 x 1024]
    bf16*  wcat = (bf16*)(ws + (16ull << 20));          //  6 MB [3072 x 1024]
    bf16*  QKV  = (bf16*)(ws + (22ull << 20));          // 48 MB [8192 x 3072]
    float* inv  = (float*)(ws + (68ull << 20));         // 32 KB (QKV region dead by then? no:
                                                        //  QKV ends at 70MB; 68MB is inside QKV!
                                                        //  -> moved below, see invp)
    bf16*  VT   = (bf16*)(ws + (70ull << 20));          // 16 MB [1024 x 8192]
    bf16*  Z    = (bf16*)(ws + (86ull << 20));          // 128 MB [8192 x 8192] (E matrix)
    float* Pv   = (float*)(ws);                         // 32 MB partial (h_bf/wcat dead by PV)
    float* invp = (float*)(ws + (33ull << 20));         // 32 KB, after Pv, before QKV-dead zone
    (void)inv;

    // 1) convert inputs to bf16 (weights concatenated [3072,1024])
    cvt_f32_to_bf16<<<8192, 256, 0, stream>>>(h,  h_bf, (8192 * 1024) / 4);
    cvt_f32_to_bf16<<<1024, 256, 0, stream>>>(wq, wcat,               (1024 * 1024) / 4);
    cvt_f32_to_bf16<<<1024, 256, 0, stream>>>(wk, wcat + 1024 * 1024, (1024 * 1024) / 4);
    cvt_f32_to_bf16<<<1024, 256, 0, stream>>>(wv, wcat + 2048 * 1024, (1024 * 1024) / 4);

    // 2) QKV = h @ wcat^T : [8192 x 3072], grid 384
    gemmW<bf16, 256, 1, 0><<<384, 512, 0, stream>>>(h_bf, wcat, QKV, nullptr,
                                                    1024, 1024, 1024, 3072, 12);

    // 3) VT = V^T (V = QKV[:, 2048:3072], row stride 3072)
    transpose_bf16<<<dim3(32, 256), dim3(32, 8), 0, stream>>>(
        (const ushort*)(QKV + 2048), (ushort*)VT, 8192, 3072);

    // 4) E = exp((Q @ K^T)/32), unnormalized softmax numerator, grid 1024
    gemmW<bf16, 256, 1, 1><<<1024, 512, 0, stream>>>(QKV, QKV + 1024, Z, nullptr,
                                                     1024, 3072, 3072, 8192, 32);

    // 5) inv[row] = 1 / rowsum(E)   (h_bf/wcat/QKV all dead now)
    rowsum_inv<<<8192, 256, 0, stream>>>(Z, invp, 8192);

    // 6) out_partials = E @ V: split-K=2 at BN=256, grid 32m x 4n x 2s = 256
    gemmW<float, 256, 2, 0><<<256, 512, 0, stream>>>(Z, VT, out, Pv,
                                                     4096, 8192, 8192, 1024, 4);

    // 7) out = (P0 + P1) * inv[row]
    add_scale<<<8192, 256, 0, stream>>>(out, Pv, invp, (8192 * 1024) / 4);
}

// Round 10
// 344.865 us; speedup vs baseline: 1.3603x; 1.0942x over previous
//
#include <hip/hip_runtime.h>
#include <hip/hip_bf16.h>
#include <stdint.h>
#include <math.h>

typedef __bf16 bf16;
typedef __bf16 bf16x8 __attribute__((ext_vector_type(8)));
typedef __bf16 bf16x4 __attribute__((ext_vector_type(4)));
typedef float  f32x4  __attribute__((ext_vector_type(4)));
typedef int    i32x4  __attribute__((ext_vector_type(4)));
typedef int    i32x16 __attribute__((ext_vector_type(16)));

#define AS_GLOBAL __attribute__((address_space(1)))
#define AS_LDS    __attribute__((address_space(3)))

__device__ __forceinline__ void gload_lds16(const void* g, void* l) {
    __builtin_amdgcn_global_load_lds((const AS_GLOBAL uint32_t*)g,
                                     (AS_LDS uint32_t*)l, 16, 0, 0);
}
__device__ __forceinline__ void cfence() { asm volatile("" ::: "memory"); }
#define BAR()    do { cfence(); __builtin_amdgcn_s_barrier(); cfence(); } while (0)
#define WAITV(n) asm volatile("s_waitcnt vmcnt(" #n ")" ::: "memory")
#define WAITL0() asm volatile("s_waitcnt lgkmcnt(0)" ::: "memory")

#define QSC 36.0f                            // q/k int8 scale (|q| tail 5.5σ≈3.2 < 127/36)
#define QDQ (1.0f / (QSC * QSC * 32.0f))     // logit dequant incl 1/sqrt(1024)

__device__ __forceinline__ int qi8(float f) {
    int q = (int)rintf(f);
    return q > 127 ? 127 : (q < -127 ? -127 : q);
}

// ---------------- convert fp32 -> bf16, 4 elems/thread ----------------
__global__ __launch_bounds__(256) void cvt_f32_to_bf16(const float* __restrict__ in,
                                                       bf16* __restrict__ out, int n4) {
    int i = blockIdx.x * 256 + threadIdx.x;
    if (i >= n4) return;
    const float4* p = (const float4*)in;
    float4 v = p[i];
    bf16x4 o;
    o[0] = (bf16)v.x; o[1] = (bf16)v.y; o[2] = (bf16)v.z; o[3] = (bf16)v.w;
    *(bf16x4*)(out + (size_t)i * 4) = o;
}

// ---- Q,K panels of QKV (bf16, ld=3072) -> int8 (scale 36), 8 elems/thread ----
__global__ __launch_bounds__(256) void cvt_qk_i8(const bf16* __restrict__ QKV,
                                                 int8_t* __restrict__ Qi8,
                                                 int8_t* __restrict__ Ki8) {
    int i = blockIdx.x * 256 + threadIdx.x;
    int base = i * 8;
    int row = base >> 11;
    int c = base & 2047;
    bf16x8 v = *(const bf16x8*)(QKV + (size_t)row * 3072 + c);
    uint32_t w0 = 0, w1 = 0;
    #pragma unroll
    for (int j = 0; j < 4; ++j) w0 |= (uint32_t)(qi8((float)v[j] * QSC) & 0xff) << (8 * j);
    #pragma unroll
    for (int j = 0; j < 4; ++j) w1 |= (uint32_t)(qi8((float)v[j + 4] * QSC) & 0xff) << (8 * j);
    int8_t* dst = (c < 1024) ? (Qi8 + (size_t)row * 1024 + c)
                             : (Ki8 + (size_t)row * 1024 + (c - 1024));
    uint2 pk; pk.x = w0; pk.y = w1;
    *(uint2*)dst = pk;
}

// ====== int8 QK^T -> bf16 E = exp(acc/41472). r9-verified geometry ======
// 256x256 tile, BK=128 bytes, 512 thr = 8 waves (2M x 4N), wave tile 128x64
// via 32x32x32 i8 MFMA (4m x 2n x 4k). A/B frag: row = lane&31,
// k = (lane>>5)*16 + [0,16) bytes. C/D: col = lane&31,
// row = (reg&3)+8*(reg>>2)+4*(lane>>5)  [m74/m101, r8/r9-verified].
// 2-window schedule (r7-proven): W1 {stage B1(t+1); 24 ds_reads; 16 MFMA mlo;
// lgkmcnt(0); bar}  W2 {stage A0,A1,B0(t+2); 16 MFMA mhi; vmcnt(6); bar}.
// XOR swizzle 16B-slot ^= (row&7) via inverse-swizzled global source.
__global__ __launch_bounds__(512, 2) void gemmEi8(const int8_t* __restrict__ A,
                                                  const int8_t* __restrict__ B,
                                                  bf16* __restrict__ E,
                                                  int K, int ld, int ldc, int nbn) {
    __shared__ char smem[131072];   // A dbuf 2x32KB @0 | B dbuf 2x32KB @65536

    const int tid  = threadIdx.x;
    const int lane = tid & 63;
    const int wave = tid >> 6;
    const int wr   = wave >> 2;           // 0..1
    const int wc   = wave & 3;            // 0..3

    const int cpx = gridDim.x >> 3;
    const int swz = ((int)blockIdx.x & 7) * cpx + ((int)blockIdx.x >> 3);
    const int bm = swz / nbn, bn = swz % nbn;
    const int NT = K >> 7;                // 8

    const int r0 = tid >> 3;
    const int c0 = ((tid & 7) ^ (r0 & 7)) << 4;     // inv-swizzled byte col
    const int8_t* Abase = A + (size_t)(bm * 256 + r0) * ld + c0;
    const int8_t* Bbase = B + (size_t)(bn * 256 + r0) * ld + c0;

    auto stA = [&](int t, int h) {
        char* d = smem + ((t & 1) << 15) + (h << 14) + (tid << 4);
        gload_lds16(Abase + ((size_t)(h * 128)     ) * ld + t * 128, d);
        gload_lds16(Abase + ((size_t)(h * 128) + 64) * ld + t * 128, d + 8192);
    };
    auto stB = [&](int t, int h) {
        char* d = smem + 65536 + ((t & 1) << 15) + (h << 14) + (tid << 4);
        gload_lds16(Bbase + ((size_t)(h * 128)     ) * ld + t * 128, d);
        gload_lds16(Bbase + ((size_t)(h * 128) + 64) * ld + t * 128, d + 8192);
    };
    auto rdFrag = [&](const char* hbase, int rr, int kk) -> i32x4 {
        int slot = ((kk << 1) + (lane >> 5)) ^ (rr & 7);
        return *(const i32x4*)(hbase + rr * 128 + (slot << 4));
    };
    auto rdA = [&](int t, int m, int kk) -> i32x4 {
        const char* hb = smem + ((t & 1) << 15) + (wr << 14);
        return rdFrag(hb, m * 32 + (lane & 31), kk);
    };
    auto rdB = [&](int t, int n, int kk) -> i32x4 {
        int gr = wc * 64 + n * 32 + (lane & 31);
        const char* hb = smem + 65536 + ((t & 1) << 15) + ((gr >> 7) << 14);
        return rdFrag(hb, gr & 127, kk);
    };

    i32x16 acc[4][2] = {};
    i32x4 a[4][4], b[2][4];

#define MM16(MO) \
    _Pragma("unroll") for (int m_ = 0; m_ < 2; ++m_) \
    _Pragma("unroll") for (int n_ = 0; n_ < 2; ++n_) \
    _Pragma("unroll") for (int k_ = 0; k_ < 4; ++k_) \
        acc[m_ + MO][n_] = __builtin_amdgcn_mfma_i32_32x32x32_i8( \
            a[m_ + MO][k_], b[n_][k_], acc[m_ + MO][n_], 0, 0, 0);

    // prologue: tile0 (8 loads) + tile1 A0,A1,B0 (6); vmcnt(6) -> tile0 landed
    stA(0, 0); stA(0, 1); stB(0, 0); stB(0, 1);
    stA(1, 0); stA(1, 1); stB(1, 0);
    WAITV(6);
    BAR();

    for (int t = 0; t < NT; ++t) {
        // ---------- window 1 ----------
        if (t + 1 < NT) stB(t + 1, 1);
        #pragma unroll
        for (int m_ = 0; m_ < 4; ++m_)
            #pragma unroll
            for (int k_ = 0; k_ < 4; ++k_) a[m_][k_] = rdA(t, m_, k_);
        #pragma unroll
        for (int n_ = 0; n_ < 2; ++n_)
            #pragma unroll
            for (int k_ = 0; k_ < 4; ++k_) b[n_][k_] = rdB(t, n_, k_);
        __builtin_amdgcn_s_setprio(1);
        MM16(0);
        __builtin_amdgcn_s_setprio(0);
        WAITL0();
        BAR();
        // ---------- window 2 ----------
        if (t + 2 < NT) { stA(t + 2, 0); stA(t + 2, 1); stB(t + 2, 0); }
        __builtin_amdgcn_s_setprio(1);
        MM16(2);
        __builtin_amdgcn_s_setprio(0);
        if (t + 2 < NT)      { WAITV(6); }
        else if (t + 1 < NT) { WAITV(0); }
        BAR();
    }
#undef MM16

    // epilogue: E = exp(acc * QDQ), bf16, 32x32 C/D layout
    const int crow0 = bm * 256 + wr * 128 + 4 * (lane >> 5);
    const int ccol0 = bn * 256 + wc * 64 + (lane & 31);
    #pragma unroll
    for (int mi = 0; mi < 4; ++mi)
        #pragma unroll
        for (int ni = 0; ni < 2; ++ni)
            #pragma unroll
            for (int r = 0; r < 16; ++r) {
                int row = crow0 + mi * 32 + (r & 3) + 8 * (r >> 2);
                E[(size_t)row * ldc + ccol0 + ni * 32] =
                    (bf16)__expf((float)acc[mi][ni][r] * QDQ);
            }
}

// ====== 2-window/K-tile bf16 GEMM (r7, verified): C = A * B^T (+split-K) ======
template<typename CT, int BN, int SPLIT>
__global__ __launch_bounds__(512, 2) void gemmW(const bf16* __restrict__ A,
                                                const bf16* __restrict__ B,
                                                CT* __restrict__ C,
                                                CT* __restrict__ C2,
                                                int K, int lda, int ldb, int ldc,
                                                int nbn) {
    constexpr int NBH = BN / 128;
    constexpr int NR  = BN / 64;
    constexpr int NHF = NR / 2;
    __shared__ char smem[65536 + NBH * 32768];

    const int tid  = threadIdx.x;
    const int lane = tid & 63;
    const int wave = tid >> 6;
    const int wr   = wave >> 2;
    const int wc   = wave & 3;
    const int frow = lane & 15;
    const int fg   = lane >> 4;

    const int cpx = gridDim.x >> 3;
    const int swz = ((int)blockIdx.x & 7) * cpx + ((int)blockIdx.x >> 3);
    int id = swz, s = 0;
    if (SPLIT == 2) { s = id & 1; id >>= 1; }
    const int bm = id / nbn, bn = id % nbn;
    const int NT = K >> 6;
    const size_t koff = (size_t)s * K;
    CT* Cp = (SPLIT == 2 && s == 1) ? C2 : C;

    const int r0 = tid >> 3;
    const int c0 = ((tid & 7) ^ (r0 & 7)) << 3;
    const bf16* Abase = A + (size_t)(bm * 256 + r0) * lda + c0 + koff;
    const bf16* Bbase = B + (size_t)(bn * BN + r0) * ldb + c0 + koff;

    auto stA = [&](int t, int h) {
        char* d = smem + ((t & 1) << 15) + (h << 14) + (tid << 4);
        gload_lds16(Abase + ((size_t)(h * 128)      ) * lda + t * 64, d);
        gload_lds16(Abase + ((size_t)(h * 128) + 64 ) * lda + t * 64, d + 8192);
    };
    auto stB = [&](int t, int h) {
        char* d = smem + 65536 + (t & 1) * (NBH * 16384) + (h << 14) + (tid << 4);
        gload_lds16(Bbase + ((size_t)(h * 128)      ) * ldb + t * 64, d);
        gload_lds16(Bbase + ((size_t)(h * 128) + 64 ) * ldb + t * 64, d + 8192);
    };
    auto rdA = [&](int t, int m, int kk) -> bf16x8 {
        int r = m * 16 + frow;
        return *(const bf16x8*)(smem + ((t & 1) << 15) + (wr << 14)
                + r * 128 + ((((kk << 2) + fg) ^ (frow & 7)) << 4));
    };
    auto rdB = [&](int t, int n, int kk) -> bf16x8 {
        int br = wc * (BN / 4) + n * 16 + frow;
        return *(const bf16x8*)(smem + 65536 + (t & 1) * (NBH * 16384) + ((br >> 7) << 14)
                + (br & 127) * 128 + ((((kk << 2) + fg) ^ (frow & 7)) << 4));
    };

    f32x4 acc[8][NR] = {};
    bf16x8 aLo[4][2], aHi[4][2], bLo[NHF][2], bHi[NHF][2];

#define MMQ(MO, NO, AARR, BARR) \
    _Pragma("unroll") for (int m_ = 0; m_ < 4; ++m_) \
    _Pragma("unroll") for (int n_ = 0; n_ < NHF; ++n_) \
    _Pragma("unroll") for (int k_ = 0; k_ < 2; ++k_) \
        acc[m_ + MO][n_ + NO] = __builtin_amdgcn_mfma_f32_16x16x32_bf16( \
            AARR[m_][k_], BARR[n_][k_], acc[m_ + MO][n_ + NO], 0, 0, 0);

    stA(0, 0); stA(0, 1);
    stB(0, 0); if constexpr (NBH == 2) stB(0, 1);
    stA(1, 0); stA(1, 1);
    if constexpr (NBH == 2) { stB(1, 0); WAITV(6); } else { WAITV(4); }
    BAR();

    for (int t = 0; t < NT; ++t) {
        if (t + 1 < NT) stB(t + 1, NBH - 1);
        #pragma unroll
        for (int m_ = 0; m_ < 4; ++m_) { aLo[m_][0] = rdA(t, m_, 0); aLo[m_][1] = rdA(t, m_, 1); }
        #pragma unroll
        for (int n_ = 0; n_ < NHF; ++n_) { bLo[n_][0] = rdB(t, n_, 0); bLo[n_][1] = rdB(t, n_, 1); }
        #pragma unroll
        for (int n_ = 0; n_ < NHF; ++n_) { bHi[n_][0] = rdB(t, NHF + n_, 0); bHi[n_][1] = rdB(t, NHF + n_, 1); }
        #pragma unroll
        for (int m_ = 0; m_ < 4; ++m_) { aHi[m_][0] = rdA(t, 4 + m_, 0); aHi[m_][1] = rdA(t, 4 + m_, 1); }
        __builtin_amdgcn_s_setprio(1);
        MMQ(0, 0, aLo, bLo);
        MMQ(0, NHF, aLo, bHi);
        __builtin_amdgcn_s_setprio(0);
        WAITL0();
        BAR();
        if (t + 2 < NT) {
            stA(t + 2, 0); stA(t + 2, 1);
            if constexpr (NBH == 2) stB(t + 2, 0);
        }
        __builtin_amdgcn_s_setprio(1);
        MMQ(4, NHF, aHi, bHi);
        MMQ(4, 0, aHi, bLo);
        __builtin_amdgcn_s_setprio(0);
        if (t + 2 < NT) {
            if constexpr (NBH == 2) WAITV(6); else WAITV(4);
        } else if (t + 1 < NT) {
            WAITV(0);
        }
        BAR();
    }
#undef MMQ

    const size_t crow0 = (size_t)bm * 256 + wr * 128 + (fg << 2);
    const size_t ccol0 = (size_t)bn * BN + wc * (BN / 4) + frow;
    #pragma unroll
    for (int m = 0; m < 8; ++m)
        #pragma unroll
        for (int n = 0; n < NR; ++n)
            #pragma unroll
            for (int i = 0; i < 4; ++i)
                Cp[(crow0 + m * 16 + i) * ldc + ccol0 + n * 16] = (CT)(acc[m][n][i]);
}

// ------- rowsum of E [rows x 8192] bf16 -> inv[row] = 1/sum -------
__global__ __launch_bounds__(256) void rowsum_inv(const bf16* __restrict__ E,
                                                  float* __restrict__ inv, int cols) {
    __shared__ float red[4];
    const int tid = threadIdx.x;
    const bf16* er = E + (size_t)blockIdx.x * cols;
    float s = 0.f;
    #pragma unroll
    for (int it = 0; it < 4; ++it) {
        bf16x8 v = *(const bf16x8*)(er + it * 2048 + tid * 8);
        #pragma unroll
        for (int j = 0; j < 8; ++j) s += (float)v[j];
    }
    #pragma unroll
    for (int o = 32; o; o >>= 1) s += __shfl_xor(s, o);
    if ((tid & 63) == 0) red[tid >> 6] = s;
    __syncthreads();
    if (tid == 0) inv[blockIdx.x] = 1.0f / (red[0] + red[1] + red[2] + red[3]);
}

// ------- out[i] = (out[i] + part[i]) * inv[row], float4 -------
__global__ __launch_bounds__(256) void add_scale(float* __restrict__ out,
                                                 const float* __restrict__ part,
                                                 const float* __restrict__ inv, int n4) {
    int i = blockIdx.x * 256 + threadIdx.x;
    if (i >= n4) return;
    const float sc = inv[i >> 8];
    float4 a = ((const float4*)out)[i];
    float4 b = ((const float4*)part)[i];
    a.x = (a.x + b.x) * sc; a.y = (a.y + b.y) * sc;
    a.z = (a.z + b.z) * sc; a.w = (a.w + b.w) * sc;
    ((float4*)out)[i] = a;
}

// ------- bf16 transpose with input row stride: VT[c][r] = V[r*ld + c] -------
__global__ __launch_bounds__(256) void transpose_bf16(const ushort* __restrict__ V,
                                                      ushort* __restrict__ VT,
                                                      int R, int ld) {
    __shared__ ushort tile[32][33];
    const int tx = threadIdx.x, ty = threadIdx.y;
    const int r0 = blockIdx.y * 32, c0 = blockIdx.x * 32;
    #pragma unroll
    for (int i = 0; i < 32; i += 8)
        tile[ty + i][tx] = V[(size_t)(r0 + ty + i) * ld + c0 + tx];
    __syncthreads();
    #pragma unroll
    for (int i = 0; i < 32; i += 8)
        VT[(size_t)(c0 + ty + i) * R + r0 + tx] = tile[tx][ty + i];
}

extern "C" void kernel_launch(void* const* d_in, const int* in_sizes, int n_in,
                              void* d_out, int out_size, void* d_ws, size_t ws_size,
                              hipStream_t stream) {
    const float* h  = (const float*)d_in[0];
    const float* wq = (const float*)d_in[1];
    const float* wk = (const float*)d_in[2];
    const float* wv = (const float*)d_in[3];
    float* out = (float*)d_out;

    char* ws = (char*)d_ws;
    bf16*   h_bf = (bf16*)(ws);                         // 16 MB [8192 x 1024]
    bf16*   wcat = (bf16*)(ws + (16ull << 20));         //  6 MB [3072 x 1024]
    bf16*   QKV  = (bf16*)(ws + (22ull << 20));         // 48 MB [8192 x 3072]
    bf16*   VT   = (bf16*)(ws + (70ull << 20));         // 16 MB [1024 x 8192]
    bf16*   E    = (bf16*)(ws + (86ull << 20));         // 128 MB [8192 x 8192]
    int8_t* Qi8  = (int8_t*)(ws);                       //  8 MB (h_bf dead post-QKV)
    int8_t* Ki8  = (int8_t*)(ws + (8ull << 20));        //  8 MB
    float*  Pv   = (float*)(ws);                        // 32 MB (Qi8/Ki8 dead by PV)
    float*  invp = (float*)(ws + (33ull << 20));        // 32 KB (QKV dead by rowsum)

    // 1) inputs -> bf16 (weights concatenated [3072,1024])
    cvt_f32_to_bf16<<<8192, 256, 0, stream>>>(h,  h_bf, (8192 * 1024) / 4);
    cvt_f32_to_bf16<<<1024, 256, 0, stream>>>(wq, wcat,               (1024 * 1024) / 4);
    cvt_f32_to_bf16<<<1024, 256, 0, stream>>>(wk, wcat + 1024 * 1024, (1024 * 1024) / 4);
    cvt_f32_to_bf16<<<1024, 256, 0, stream>>>(wv, wcat + 2048 * 1024, (1024 * 1024) / 4);

    // 2) QKV = h @ wcat^T : [8192 x 3072], bf16 GEMM, grid 384
    gemmW<bf16, 256, 1><<<384, 512, 0, stream>>>(h_bf, wcat, QKV, nullptr,
                                                 1024, 1024, 1024, 3072, 12);

    // 3) Q,K -> int8 (scale 36), overwriting dead h_bf region
    cvt_qk_i8<<<8192, 256, 0, stream>>>(QKV, Qi8, Ki8);

    // 4) VT = V^T, bf16 (V = QKV[:, 2048:3072])
    transpose_bf16<<<dim3(32, 256), dim3(32, 8), 0, stream>>>(
        (const ushort*)(QKV + 2048), (ushort*)VT, 8192, 3072);

    // 5) E = exp((Qi8 . Ki8) / 41472), int8 MFMA, bf16 out, grid 1024
    gemmEi8<<<1024, 512, 0, stream>>>(Qi8, Ki8, E, 1024, 1024, 8192, 32);

    // 6) inv[row] = 1 / rowsum(E)
    rowsum_inv<<<8192, 256, 0, stream>>>(E, invp, 8192);

    // 7) P = E @ VT^T (bf16, split-K=2, grid 256)
    gemmW<float, 256, 2><<<256, 512, 0, stream>>>(E, VT, out, Pv,
                                                  4096, 8192, 8192, 1024, 4);

    // 8) out = (P0 + P1) * inv[row]
    add_scale<<<8192, 256, 0, stream>>>(out, Pv, invp, (8192 * 1024) / 4);
}